// Round 1
// baseline (1897.174 us; speedup 1.0000x reference)
//
#include <hip/hip_runtime.h>
#include <hip/hip_bf16.h>
#include <stdint.h>

// GraphCON-GCN on MI355X.
// Key algebra: with DT=ALPHA=GAMMA=1, Xs_{l+1} = relu(gcn+res); Y drops out.
// Scatter commutes with the linear map: z = (A.Xs + (dinv^2-1)Xs) Wc^T + Xs Wr^T + (b_c+b_r).
// GEMMs run as split-bf16 (hi+lo) MFMA: 3 mfma per tile ~ fp32 accuracy.

#define HD 128   // hidden width (= F = H in the reference)

typedef __attribute__((ext_vector_type(8))) short bf16x8;
typedef __attribute__((ext_vector_type(4))) float f32x4;

__device__ __forceinline__ unsigned short f2bf(float f){
  unsigned u = __float_as_uint(f);
  u += 0x7fffu + ((u >> 16) & 1u);
  return (unsigned short)(u >> 16);
}
__device__ __forceinline__ float bf2f(unsigned short h){
  return __uint_as_float(((unsigned)h) << 16);
}

// ---- CSR build ------------------------------------------------------------
__global__ __launch_bounds__(256) void k_deg(const int* __restrict__ dst, int E,
                                             int* __restrict__ cnt){
  int e = blockIdx.x * 256 + threadIdx.x;
  if (e < E) atomicAdd(&cnt[dst[e]], 1);
}

__global__ __launch_bounds__(256) void k_dinv(const int* __restrict__ cnt,
                                              float* __restrict__ dinv, int N){
  int i = blockIdx.x * 256 + threadIdx.x;
  if (i < N) dinv[i] = rsqrtf((float)cnt[i] + 1.0f);
}

// single-block exclusive scan over cnt[N] -> rp[N+1]
__global__ __launch_bounds__(1024) void k_scan(const int* __restrict__ cnt,
                                               int* __restrict__ rp, int N){
  __shared__ int part[1024];
  int t = threadIdx.x;
  int chunk = (N + 1023) >> 10;
  int lo = t * chunk;
  int hi = min(lo + chunk, N);
  int s = 0;
  for (int i = lo; i < hi; ++i) s += cnt[i];
  part[t] = s;
  __syncthreads();
  for (int off = 1; off < 1024; off <<= 1){
    int v = (t >= off) ? part[t - off] : 0;
    __syncthreads();
    part[t] += v;
    __syncthreads();
  }
  int base = (t == 0) ? 0 : part[t - 1];
  for (int i = lo; i < hi; ++i){ rp[i] = base; base += cnt[i]; }
  if (t == 1023) rp[N] = part[1023];
}

__global__ __launch_bounds__(256) void k_fill(const int* __restrict__ src,
                                              const int* __restrict__ dst, int E,
                                              const int* __restrict__ rp,
                                              int* __restrict__ fill,
                                              const float* __restrict__ dinv,
                                              int* __restrict__ col,
                                              float* __restrict__ nrm){
  int e = blockIdx.x * 256 + threadIdx.x;
  if (e >= E) return;
  int s = src[e], d = dst[e];
  int pos = rp[d] + atomicAdd(&fill[d], 1);
  col[pos] = s;
  nrm[pos] = dinv[s] * dinv[d];
}

// ---- fp32 -> bf16 hi/lo split ----------------------------------------------
__global__ __launch_bounds__(256) void k_split(const float* __restrict__ in,
                                               unsigned short* __restrict__ hi,
                                               unsigned short* __restrict__ lo,
                                               int n4){
  int i = blockIdx.x * 256 + threadIdx.x;
  if (i >= n4) return;
  float4 v = ((const float4*)in)[i];
  ushort4 h, l;
  h.x = f2bf(v.x); l.x = f2bf(v.x - bf2f(h.x));
  h.y = f2bf(v.y); l.y = f2bf(v.y - bf2f(h.y));
  h.z = f2bf(v.z); l.z = f2bf(v.z - bf2f(h.z));
  h.w = f2bf(v.w); l.w = f2bf(v.w - bf2f(h.w));
  ((ushort4*)hi)[i] = h;
  ((ushort4*)lo)[i] = l;
}

__global__ __launch_bounds__(256) void k_prep_w(const float* __restrict__ Wc,
                                                const float* __restrict__ Wr,
                                                const float* __restrict__ We,
                                                const float* __restrict__ bc,
                                                const float* __restrict__ br,
                                                unsigned short* __restrict__ WcH, unsigned short* __restrict__ WcL,
                                                unsigned short* __restrict__ WrH, unsigned short* __restrict__ WrL,
                                                unsigned short* __restrict__ WeH, unsigned short* __restrict__ WeL,
                                                float* __restrict__ bias_sum){
  int i = blockIdx.x * 256 + threadIdx.x;
  if (i < HD * HD){
    float a = Wc[i]; unsigned short h = f2bf(a); WcH[i] = h; WcL[i] = f2bf(a - bf2f(h));
    float b = Wr[i]; h = f2bf(b); WrH[i] = h; WrL[i] = f2bf(b - bf2f(h));
    float c = We[i]; h = f2bf(c); WeH[i] = h; WeL[i] = f2bf(c - bf2f(h));
  }
  if (i < HD) bias_sum[i] = bc[i] + br[i];
}

// ---- per-layer aggregation: U = A.Xs + (dinv^2-1) Xs  (pull, no atomics) ---
__global__ __launch_bounds__(256) void k_agg(const float* __restrict__ Xs,
                                             const float* __restrict__ dinv,
                                             const int* __restrict__ rp,
                                             const int* __restrict__ col,
                                             const float* __restrict__ nrm,
                                             unsigned short* __restrict__ UH,
                                             unsigned short* __restrict__ UL,
                                             int N){
  int w = threadIdx.x >> 6;
  int lane = threadIdx.x & 63;
  int node = blockIdx.x * 4 + w;
  if (node >= N) return;
  float di = dinv[node];
  float self = di * di - 1.0f;
  const float2* xr = (const float2*)(Xs + (size_t)node * HD);
  float2 sv = xr[lane];
  float a0 = self * sv.x;
  float a1 = self * sv.y;
  int b = rp[node], e = rp[node + 1];
  for (int j = b; j < e; ++j){
    int s = col[j];
    float wgt = nrm[j];
    float2 v = ((const float2*)(Xs + (size_t)s * HD))[lane];
    a0 = fmaf(wgt, v.x, a0);
    a1 = fmaf(wgt, v.y, a1);
  }
  unsigned short h0 = f2bf(a0);
  unsigned short h1 = f2bf(a1);
  ushort2 hh; hh.x = h0; hh.y = h1;
  ushort2 ll; ll.x = f2bf(a0 - bf2f(h0)); ll.y = f2bf(a1 - bf2f(h1));
  ((ushort2*)(UH + (size_t)node * HD))[lane] = hh;
  ((ushort2*)(UL + (size_t)node * HD))[lane] = ll;
}

// ---- fused GEMM: out = relu?( A1 W1^T + A2 W2^T + bias ) -------------------
// Split-bf16: each product = hh + hl + lh MFMAs. One wave = 32 rows x 128 cols.
// NOTE: outH/outL alias A2h/A2l (in-place per-row update) -> no __restrict__ there.
__global__ __launch_bounds__(256) void k_gemm(
    const unsigned short* A1h, const unsigned short* A1l,
    const unsigned short* __restrict__ W1h, const unsigned short* __restrict__ W1l,
    const unsigned short* A2h, const unsigned short* A2l,
    const unsigned short* __restrict__ W2h, const unsigned short* __restrict__ W2l,
    const float* __restrict__ bias,
    float* outF, unsigned short* outH, unsigned short* outL,
    int N, int relu){
  int wid = blockIdx.x * 4 + (threadIdx.x >> 6);
  int row0 = wid * 32;
  if (row0 >= N) return;
  int lane = threadIdx.x & 63;
  int r = lane & 15;
  int kg = lane >> 4;

  f32x4 acc[2][8];
#pragma unroll
  for (int s = 0; s < 2; ++s)
#pragma unroll
    for (int c = 0; c < 8; ++c) acc[s][c] = (f32x4)0.0f;

  const bool two = (A2h != nullptr);

#pragma unroll
  for (int kst = 0; kst < 4; ++kst){
    int k0 = kst * 32 + kg * 8;
    bf16x8 a1h[2], a1l[2], a2h[2], a2l[2];
#pragma unroll
    for (int s = 0; s < 2; ++s){
      size_t ao = (size_t)(row0 + s * 16 + r) * HD + k0;
      a1h[s] = *(const bf16x8*)(A1h + ao);
      a1l[s] = *(const bf16x8*)(A1l + ao);
      if (two){
        a2h[s] = *(const bf16x8*)(A2h + ao);
        a2l[s] = *(const bf16x8*)(A2l + ao);
      }
    }
#pragma unroll
    for (int ct = 0; ct < 8; ++ct){
      size_t bo = (size_t)(ct * 16 + r) * HD + k0;
      bf16x8 b1h = *(const bf16x8*)(W1h + bo);
      bf16x8 b1l = *(const bf16x8*)(W1l + bo);
#pragma unroll
      for (int s = 0; s < 2; ++s){
        acc[s][ct] = __builtin_amdgcn_mfma_f32_16x16x32_bf16(a1h[s], b1h, acc[s][ct], 0, 0, 0);
        acc[s][ct] = __builtin_amdgcn_mfma_f32_16x16x32_bf16(a1h[s], b1l, acc[s][ct], 0, 0, 0);
        acc[s][ct] = __builtin_amdgcn_mfma_f32_16x16x32_bf16(a1l[s], b1h, acc[s][ct], 0, 0, 0);
      }
      if (two){
        bf16x8 b2h = *(const bf16x8*)(W2h + bo);
        bf16x8 b2l = *(const bf16x8*)(W2l + bo);
#pragma unroll
        for (int s = 0; s < 2; ++s){
          acc[s][ct] = __builtin_amdgcn_mfma_f32_16x16x32_bf16(a2h[s], b2h, acc[s][ct], 0, 0, 0);
          acc[s][ct] = __builtin_amdgcn_mfma_f32_16x16x32_bf16(a2h[s], b2l, acc[s][ct], 0, 0, 0);
          acc[s][ct] = __builtin_amdgcn_mfma_f32_16x16x32_bf16(a2l[s], b2h, acc[s][ct], 0, 0, 0);
        }
      }
    }
  }

  // epilogue: C/D layout col = lane&15, row = kg*4 + reg
#pragma unroll
  for (int s = 0; s < 2; ++s){
#pragma unroll
    for (int ct = 0; ct < 8; ++ct){
      int cc = ct * 16 + r;
      float bv = bias[cc];
#pragma unroll
      for (int j = 0; j < 4; ++j){
        int rr = row0 + s * 16 + kg * 4 + j;
        float v = acc[s][ct][j] + bv;
        if (relu) v = fmaxf(v, 0.0f);
        size_t o = (size_t)rr * HD + cc;
        outF[o] = v;
        unsigned short hh = f2bf(v);
        outH[o] = hh;
        outL[o] = f2bf(v - bf2f(hh));
      }
    }
  }
}

// ---- decode + segment-sum pool ---------------------------------------------
__global__ __launch_bounds__(256) void k_decode(const float* __restrict__ Xs,
                                                const float* __restrict__ Wd,
                                                const float* __restrict__ bd,
                                                const int* __restrict__ batch,
                                                float* __restrict__ out, int N){
  int w = threadIdx.x >> 6;
  int lane = threadIdx.x & 63;
  int node = blockIdx.x * 4 + w;
  if (node >= N) return;
  const float* xr = Xs + (size_t)node * HD;
  float v = xr[lane] * Wd[lane] + xr[lane + 64] * Wd[lane + 64];
#pragma unroll
  for (int off = 32; off > 0; off >>= 1) v += __shfl_down(v, off, 64);
  if (lane == 0) atomicAdd(&out[batch[node]], v + bd[0]);
}

// ---- launcher ---------------------------------------------------------------
extern "C" void kernel_launch(void* const* d_in, const int* in_sizes, int n_in,
                              void* d_out, int out_size, void* d_ws, size_t ws_size,
                              hipStream_t stream){
  const float* x      = (const float*)d_in[0];
  const int*   ei     = (const int*)d_in[1];
  const int*   batch  = (const int*)d_in[2];
  const float* W_enc  = (const float*)d_in[3];
  const float* b_enc  = (const float*)d_in[4];
  const float* W_conv = (const float*)d_in[5];
  const float* b_conv = (const float*)d_in[6];
  const float* W_res  = (const float*)d_in[7];
  const float* b_res  = (const float*)d_in[8];
  const float* W_dec  = (const float*)d_in[9];
  const float* b_dec  = (const float*)d_in[10];

  const int N = in_sizes[0] / HD;
  const int E = in_sizes[1] / 2;
  float* out = (float*)d_out;

  char* ws = (char*)d_ws;
  size_t off = 0;
  auto alloc = [&](size_t bytes) -> char* {
    char* p = ws + off;
    off += (bytes + 255) & ~(size_t)255;
    return p;
  };
  int*   cnt  = (int*)  alloc((size_t)N * 4);
  int*   fill = (int*)  alloc((size_t)N * 4);
  int*   rp   = (int*)  alloc(((size_t)N + 1) * 4);
  float* dinv = (float*)alloc((size_t)N * 4);
  int*   col  = (int*)  alloc((size_t)E * 4);
  float* nrm  = (float*)alloc((size_t)E * 4);
  float* Xs   = (float*)alloc((size_t)N * HD * 4);
  unsigned short* XsH = (unsigned short*)alloc((size_t)N * HD * 2);
  unsigned short* XsL = (unsigned short*)alloc((size_t)N * HD * 2);
  unsigned short* UH  = (unsigned short*)alloc((size_t)N * HD * 2);
  unsigned short* UL  = (unsigned short*)alloc((size_t)N * HD * 2);
  unsigned short* WcH = (unsigned short*)alloc((size_t)HD * HD * 2);
  unsigned short* WcL = (unsigned short*)alloc((size_t)HD * HD * 2);
  unsigned short* WrH = (unsigned short*)alloc((size_t)HD * HD * 2);
  unsigned short* WrL = (unsigned short*)alloc((size_t)HD * HD * 2);
  unsigned short* WeH = (unsigned short*)alloc((size_t)HD * HD * 2);
  unsigned short* WeL = (unsigned short*)alloc((size_t)HD * HD * 2);
  float* bias_sum = (float*)alloc((size_t)HD * 4);

  hipMemsetAsync(cnt,  0, (size_t)N * 4, stream);
  hipMemsetAsync(fill, 0, (size_t)N * 4, stream);
  hipMemsetAsync(out,  0, (size_t)out_size * 4, stream);

  const int* src = ei;
  const int* dst = ei + E;

  k_deg <<<(E + 255) / 256, 256, 0, stream>>>(dst, E, cnt);
  k_dinv<<<(N + 255) / 256, 256, 0, stream>>>(cnt, dinv, N);
  k_scan<<<1, 1024, 0, stream>>>(cnt, rp, N);
  k_fill<<<(E + 255) / 256, 256, 0, stream>>>(src, dst, E, rp, fill, dinv, col, nrm);

  int n4 = N * HD / 4;
  k_split<<<(n4 + 255) / 256, 256, 0, stream>>>(x, UH, UL, n4);   // UH/UL double as x hi/lo
  k_prep_w<<<(HD * HD + 255) / 256, 256, 0, stream>>>(W_conv, W_res, W_enc, b_conv, b_res,
                                                      WcH, WcL, WrH, WrL, WeH, WeL, bias_sum);

  int gemm_blocks = ((N + 31) / 32 + 3) / 4;
  int node_blocks = (N + 3) / 4;

  // encoder: Xs = x @ W_enc^T + b_enc
  k_gemm<<<gemm_blocks, 256, 0, stream>>>(UH, UL, WeH, WeL,
                                          nullptr, nullptr, nullptr, nullptr,
                                          b_enc, Xs, XsH, XsL, N, 0);

  for (int l = 0; l < 5; ++l){
    k_agg <<<node_blocks, 256, 0, stream>>>(Xs, dinv, rp, col, nrm, UH, UL, N);
    k_gemm<<<gemm_blocks, 256, 0, stream>>>(UH, UL, WcH, WcL,
                                            XsH, XsL, WrH, WrL,
                                            bias_sum, Xs, XsH, XsL, N, 1);
  }

  k_decode<<<node_blocks, 256, 0, stream>>>(Xs, W_dec, b_dec, batch, out, N);
}

// Round 2
// 1404.306 us; speedup vs baseline: 1.3510x; 1.3510x over previous
//
#include <hip/hip_runtime.h>
#include <hip/hip_bf16.h>
#include <stdint.h>

// GraphCON-GCN on MI355X.
// Algebra: with DT=ALPHA=GAMMA=1, Xs_{l+1} = relu(gcn+res); Y drops out.
// z = (A.Xs + (dinv^2-1)Xs) Wc^T + Xs Wr^T + (b_c+b_r); out = pool(Xs Wd^T + bd).
// GEMMs: split-bf16 (hi+lo) MFMA, A split done in-register from fp32 (saves
// 102MB/layer of hi/lo array writes). Decode fused into final GEMM epilogue;
// pooling via LDS histogram (avoids the 240us same-address atomic chain).

#define HD 128

typedef __attribute__((ext_vector_type(8))) short bf16x8;
typedef __attribute__((ext_vector_type(4))) float f32x4;
typedef __attribute__((ext_vector_type(8))) float f32x8;

__device__ __forceinline__ unsigned short f2bf_rn(float f){
  unsigned u = __float_as_uint(f);
  u += 0x7fffu + ((u >> 16) & 1u);
  return (unsigned short)(u >> 16);
}
__device__ __forceinline__ float bf2f(unsigned short h){
  return __uint_as_float(((unsigned)h) << 16);
}

// in-register fp32 -> bf16 hi/lo split (truncating; hi+lo captures 16 bits)
__device__ __forceinline__ void split8(const float* p, bf16x8& h, bf16x8& l){
  f32x8 v = *(const f32x8*)p;
#pragma unroll
  for (int i = 0; i < 8; ++i){
    unsigned u = __float_as_uint(v[i]);
    h[i] = (short)(u >> 16);
    float lf = v[i] - __uint_as_float(u & 0xffff0000u);
    l[i] = (short)(__float_as_uint(lf) >> 16);
  }
}

// ---- CSR build ------------------------------------------------------------
__global__ __launch_bounds__(256) void k_deg(const int* __restrict__ dst, int E,
                                             int* __restrict__ cnt){
  int e = blockIdx.x * 256 + threadIdx.x;
  if (e < E) atomicAdd(&cnt[dst[e]], 1);
}

__global__ __launch_bounds__(256) void k_dinv(const int* __restrict__ cnt,
                                              float* __restrict__ dinv, int N){
  int i = blockIdx.x * 256 + threadIdx.x;
  if (i < N) dinv[i] = rsqrtf((float)cnt[i] + 1.0f);
}

// single-block exclusive scan over cnt[N] -> rp[N+1]
__global__ __launch_bounds__(1024) void k_scan(const int* __restrict__ cnt,
                                               int* __restrict__ rp, int N){
  __shared__ int part[1024];
  int t = threadIdx.x;
  int chunk = (N + 1023) >> 10;
  int lo = t * chunk;
  int hi = min(lo + chunk, N);
  int s = 0;
  for (int i = lo; i < hi; ++i) s += cnt[i];
  part[t] = s;
  __syncthreads();
  for (int off = 1; off < 1024; off <<= 1){
    int v = (t >= off) ? part[t - off] : 0;
    __syncthreads();
    part[t] += v;
    __syncthreads();
  }
  int base = (t == 0) ? 0 : part[t - 1];
  for (int i = lo; i < hi; ++i){ rp[i] = base; base += cnt[i]; }
  if (t == 1023) rp[N] = part[1023];
}

__global__ __launch_bounds__(256) void k_fill(const int* __restrict__ src,
                                              const int* __restrict__ dst, int E,
                                              const int* __restrict__ rp,
                                              int* __restrict__ fill,
                                              const float* __restrict__ dinv,
                                              int* __restrict__ col,
                                              float* __restrict__ nrm){
  int e = blockIdx.x * 256 + threadIdx.x;
  if (e >= E) return;
  int s = src[e], d = dst[e];
  int pos = rp[d] + atomicAdd(&fill[d], 1);
  col[pos] = s;
  nrm[pos] = dinv[s] * dinv[d];
}

// ---- weight prep: fp32 -> bf16 hi/lo (round-to-nearest), bias sum ----------
__global__ __launch_bounds__(256) void k_prep_w(const float* __restrict__ Wc,
                                                const float* __restrict__ Wr,
                                                const float* __restrict__ We,
                                                const float* __restrict__ bc,
                                                const float* __restrict__ br,
                                                unsigned short* __restrict__ WcH, unsigned short* __restrict__ WcL,
                                                unsigned short* __restrict__ WrH, unsigned short* __restrict__ WrL,
                                                unsigned short* __restrict__ WeH, unsigned short* __restrict__ WeL,
                                                float* __restrict__ bias_sum){
  int i = blockIdx.x * 256 + threadIdx.x;
  if (i < HD * HD){
    float a = Wc[i]; unsigned short h = f2bf_rn(a); WcH[i] = h; WcL[i] = f2bf_rn(a - bf2f(h));
    float b = Wr[i]; h = f2bf_rn(b); WrH[i] = h; WrL[i] = f2bf_rn(b - bf2f(h));
    float c = We[i]; h = f2bf_rn(c); WeH[i] = h; WeL[i] = f2bf_rn(c - bf2f(h));
  }
  if (i < HD) bias_sum[i] = bc[i] + br[i];
}

// ---- per-layer aggregation: U = A.Xs + (dinv^2-1) Xs  (pull, no atomics) ---
__global__ __launch_bounds__(256) void k_agg(const float* __restrict__ Xs,
                                             const float* __restrict__ dinv,
                                             const int* __restrict__ rp,
                                             const int* __restrict__ col,
                                             const float* __restrict__ nrm,
                                             float* __restrict__ U,
                                             int N){
  int w = threadIdx.x >> 6;
  int lane = threadIdx.x & 63;
  int node = blockIdx.x * 4 + w;
  if (node >= N) return;
  float di = dinv[node];
  float self = di * di - 1.0f;
  float2 sv = ((const float2*)(Xs + (size_t)node * HD))[lane];
  float a0 = self * sv.x;
  float a1 = self * sv.y;
  int b = rp[node], e = rp[node + 1];
  int j = b;
  for (; j + 1 < e; j += 2){
    int s0 = col[j],     s1 = col[j + 1];
    float w0 = nrm[j],   w1 = nrm[j + 1];
    float2 v0 = ((const float2*)(Xs + (size_t)s0 * HD))[lane];
    float2 v1 = ((const float2*)(Xs + (size_t)s1 * HD))[lane];
    a0 = fmaf(w0, v0.x, a0); a1 = fmaf(w0, v0.y, a1);
    a0 = fmaf(w1, v1.x, a0); a1 = fmaf(w1, v1.y, a1);
  }
  if (j < e){
    int s0 = col[j];
    float w0 = nrm[j];
    float2 v0 = ((const float2*)(Xs + (size_t)s0 * HD))[lane];
    a0 = fmaf(w0, v0.x, a0); a1 = fmaf(w0, v0.y, a1);
  }
  float2 o; o.x = a0; o.y = a1;
  ((float2*)(U + (size_t)node * HD))[lane] = o;
}

// ---- fused GEMM: out = relu?( A1 W1^T + A2 W2^T + bias ), optional decode --
// One wave = 32 rows x 128 cols, K=128 per matrix, split-bf16 (3 MFMA/term).
// decode mode: skip stores, compute val[row] = dot(out_row, Wd) + bd[0].
__global__ __launch_bounds__(256) void k_gemm(
    const float* A1, const float* A2,
    const unsigned short* __restrict__ W1h, const unsigned short* __restrict__ W1l,
    const unsigned short* __restrict__ W2h, const unsigned short* __restrict__ W2l,
    const float* __restrict__ bias,
    float* outXs,
    const float* __restrict__ Wd, const float* __restrict__ bd,
    float* __restrict__ val,
    int N, int relu, int decode){
  int wid = blockIdx.x * 4 + (threadIdx.x >> 6);
  int row0 = wid * 32;
  if (row0 >= N) return;
  int lane = threadIdx.x & 63;
  int r = lane & 15;
  int kg = lane >> 4;

  f32x4 acc[2][8];
#pragma unroll
  for (int s = 0; s < 2; ++s)
#pragma unroll
    for (int c = 0; c < 8; ++c) acc[s][c] = (f32x4)0.0f;

  const bool two = (A2 != nullptr);

#pragma unroll
  for (int kst = 0; kst < 4; ++kst){
    int k0 = kst * 32 + kg * 8;
    bf16x8 a1h[2], a1l[2], a2h[2], a2l[2];
#pragma unroll
    for (int s = 0; s < 2; ++s){
      size_t ao = (size_t)(row0 + s * 16 + r) * HD + k0;
      split8(A1 + ao, a1h[s], a1l[s]);
      if (two) split8(A2 + ao, a2h[s], a2l[s]);
    }
#pragma unroll
    for (int ct = 0; ct < 8; ++ct){
      size_t bo = (size_t)(ct * 16 + r) * HD + k0;
      bf16x8 b1h = *(const bf16x8*)(W1h + bo);
      bf16x8 b1l = *(const bf16x8*)(W1l + bo);
#pragma unroll
      for (int s = 0; s < 2; ++s){
        acc[s][ct] = __builtin_amdgcn_mfma_f32_16x16x32_bf16(a1h[s], b1h, acc[s][ct], 0, 0, 0);
        acc[s][ct] = __builtin_amdgcn_mfma_f32_16x16x32_bf16(a1h[s], b1l, acc[s][ct], 0, 0, 0);
        acc[s][ct] = __builtin_amdgcn_mfma_f32_16x16x32_bf16(a1l[s], b1h, acc[s][ct], 0, 0, 0);
      }
      if (two){
        bf16x8 b2h = *(const bf16x8*)(W2h + bo);
        bf16x8 b2l = *(const bf16x8*)(W2l + bo);
#pragma unroll
        for (int s = 0; s < 2; ++s){
          acc[s][ct] = __builtin_amdgcn_mfma_f32_16x16x32_bf16(a2h[s], b2h, acc[s][ct], 0, 0, 0);
          acc[s][ct] = __builtin_amdgcn_mfma_f32_16x16x32_bf16(a2h[s], b2l, acc[s][ct], 0, 0, 0);
          acc[s][ct] = __builtin_amdgcn_mfma_f32_16x16x32_bf16(a2l[s], b2h, acc[s][ct], 0, 0, 0);
        }
      }
    }
  }

  // epilogue: C/D layout col = lane&15, row = kg*4 + reg
  float rowp[2][4] = {{0.f,0.f,0.f,0.f},{0.f,0.f,0.f,0.f}};
#pragma unroll
  for (int s = 0; s < 2; ++s){
#pragma unroll
    for (int ct = 0; ct < 8; ++ct){
      int cc = ct * 16 + r;
      float bv = bias[cc];
      float wdv = decode ? Wd[cc] : 0.f;
#pragma unroll
      for (int j = 0; j < 4; ++j){
        float v = acc[s][ct][j] + bv;
        if (relu) v = fmaxf(v, 0.0f);
        if (decode){
          rowp[s][j] += v * wdv;
        } else {
          int rr = row0 + s * 16 + kg * 4 + j;
          outXs[(size_t)rr * HD + cc] = v;
        }
      }
    }
  }
  if (decode){
    float bd0 = bd[0];
#pragma unroll
    for (int s = 0; s < 2; ++s)
#pragma unroll
      for (int j = 0; j < 4; ++j){
        float t = rowp[s][j];
        t += __shfl_xor(t, 1, 64);
        t += __shfl_xor(t, 2, 64);
        t += __shfl_xor(t, 4, 64);
        t += __shfl_xor(t, 8, 64);
        if (r == 0) val[row0 + s * 16 + kg * 4 + j] = t + bd0;
      }
  }
}

// ---- pooling: LDS histogram per block, few global atomics ------------------
#define POOL_CHUNK 1024
__global__ __launch_bounds__(256) void k_pool(const float* __restrict__ val,
                                              const int* __restrict__ batch,
                                              float* __restrict__ out, int N, int G){
  __shared__ float acc[4096];
  int t = threadIdx.x;
  int lo = blockIdx.x * POOL_CHUNK;
  int hi = min(lo + POOL_CHUNK, N);
  if (G <= 4096){
    for (int i = t; i < G; i += 256) acc[i] = 0.f;
    __syncthreads();
    for (int i = lo + t; i < hi; i += 256) atomicAdd(&acc[batch[i]], val[i]);
    __syncthreads();
    for (int i = t; i < G; i += 256){
      float v = acc[i];
      if (v != 0.f) atomicAdd(&out[i], v);
    }
  } else {
    for (int i = lo + t; i < hi; i += 256) atomicAdd(&out[batch[i]], val[i]);
  }
}

// ---- launcher ---------------------------------------------------------------
extern "C" void kernel_launch(void* const* d_in, const int* in_sizes, int n_in,
                              void* d_out, int out_size, void* d_ws, size_t ws_size,
                              hipStream_t stream){
  const float* x      = (const float*)d_in[0];
  const int*   ei     = (const int*)d_in[1];
  const int*   batch  = (const int*)d_in[2];
  const float* W_enc  = (const float*)d_in[3];
  const float* b_enc  = (const float*)d_in[4];
  const float* W_conv = (const float*)d_in[5];
  const float* b_conv = (const float*)d_in[6];
  const float* W_res  = (const float*)d_in[7];
  const float* b_res  = (const float*)d_in[8];
  const float* W_dec  = (const float*)d_in[9];
  const float* b_dec  = (const float*)d_in[10];

  const int N = in_sizes[0] / HD;
  const int E = in_sizes[1] / 2;
  float* out = (float*)d_out;

  char* ws = (char*)d_ws;
  size_t off = 0;
  auto alloc = [&](size_t bytes) -> char* {
    char* p = ws + off;
    off += (bytes + 255) & ~(size_t)255;
    return p;
  };
  int*   cnt  = (int*)  alloc((size_t)N * 4);
  int*   fill = (int*)  alloc((size_t)N * 4);
  int*   rp   = (int*)  alloc(((size_t)N + 1) * 4);
  float* dinv = (float*)alloc((size_t)N * 4);
  int*   col  = (int*)  alloc((size_t)E * 4);
  float* nrm  = (float*)alloc((size_t)E * 4);
  float* Xs   = (float*)alloc((size_t)N * HD * 4);
  float* U    = (float*)alloc((size_t)N * HD * 4);
  float* val  = (float*)alloc((size_t)N * 4);
  unsigned short* WcH = (unsigned short*)alloc((size_t)HD * HD * 2);
  unsigned short* WcL = (unsigned short*)alloc((size_t)HD * HD * 2);
  unsigned short* WrH = (unsigned short*)alloc((size_t)HD * HD * 2);
  unsigned short* WrL = (unsigned short*)alloc((size_t)HD * HD * 2);
  unsigned short* WeH = (unsigned short*)alloc((size_t)HD * HD * 2);
  unsigned short* WeL = (unsigned short*)alloc((size_t)HD * HD * 2);
  float* bias_sum = (float*)alloc((size_t)HD * 4);

  hipMemsetAsync(cnt,  0, (size_t)N * 4, stream);
  hipMemsetAsync(fill, 0, (size_t)N * 4, stream);
  hipMemsetAsync(out,  0, (size_t)out_size * 4, stream);

  const int* src = ei;
  const int* dst = ei + E;

  k_deg <<<(E + 255) / 256, 256, 0, stream>>>(dst, E, cnt);
  k_dinv<<<(N + 255) / 256, 256, 0, stream>>>(cnt, dinv, N);
  k_scan<<<1, 1024, 0, stream>>>(cnt, rp, N);
  k_fill<<<(E + 255) / 256, 256, 0, stream>>>(src, dst, E, rp, fill, dinv, col, nrm);
  k_prep_w<<<(HD * HD + 255) / 256, 256, 0, stream>>>(W_conv, W_res, W_enc, b_conv, b_res,
                                                      WcH, WcL, WrH, WrL, WeH, WeL, bias_sum);

  int gemm_blocks = ((N + 31) / 32 + 3) / 4;
  int node_blocks = (N + 3) / 4;

  // encoder: Xs = x @ W_enc^T + b_enc   (no relu)
  k_gemm<<<gemm_blocks, 256, 0, stream>>>(x, nullptr, WeH, WeL, nullptr, nullptr,
                                          b_enc, Xs, nullptr, nullptr, nullptr, N, 0, 0);

  for (int l = 0; l < 5; ++l){
    k_agg<<<node_blocks, 256, 0, stream>>>(Xs, dinv, rp, col, nrm, U, N);
    int last = (l == 4);
    k_gemm<<<gemm_blocks, 256, 0, stream>>>(U, Xs, WcH, WcL, WrH, WrL,
                                            bias_sum, Xs,
                                            W_dec, b_dec, val, N, 1, last);
  }

  k_pool<<<(N + POOL_CHUNK - 1) / POOL_CHUNK, 256, 0, stream>>>(val, batch, out, N, out_size);
}

// Round 3
// 1218.840 us; speedup vs baseline: 1.5565x; 1.1522x over previous
//
#include <hip/hip_runtime.h>
#include <hip/hip_bf16.h>
#include <stdint.h>

// GraphCON-GCN on MI355X.
// Algebra: with DT=ALPHA=GAMMA=1, Xs_{l+1} = relu(gcn+res); Y drops out.
// z = (A.Xs + (dinv^2-1)Xs) Wc^T + Xs Wr^T + (b_c+b_r); out = pool(Xs Wd^T + bd).
// GEMMs: split-bf16 (hi+lo) MFMA, A split in-register from fp32.
// Decode fused into final GEMM epilogue; pooling via LDS histogram.
// Scan is 3-phase multi-block (the 1-block scan was 159us of serial latency).
// k_agg: half-wave-per-edge float4 gathers, 4 gathers in flight per wave.

#define HD 128
#define SCHUNK 2048   // scan elements per block (256 thr * 8)

typedef __attribute__((ext_vector_type(8))) short bf16x8;
typedef __attribute__((ext_vector_type(4))) float f32x4;
typedef __attribute__((ext_vector_type(8))) float f32x8;

__device__ __forceinline__ unsigned short f2bf_rn(float f){
  unsigned u = __float_as_uint(f);
  u += 0x7fffu + ((u >> 16) & 1u);
  return (unsigned short)(u >> 16);
}
__device__ __forceinline__ float bf2f(unsigned short h){
  return __uint_as_float(((unsigned)h) << 16);
}

// in-register fp32 -> bf16 hi/lo split (truncating hi; hi+lo ~ 2^-17 rel)
__device__ __forceinline__ void split8(const float* p, bf16x8& h, bf16x8& l){
  f32x8 v = *(const f32x8*)p;
#pragma unroll
  for (int i = 0; i < 8; ++i){
    unsigned u = __float_as_uint(v[i]);
    h[i] = (short)(u >> 16);
    float lf = v[i] - __uint_as_float(u & 0xffff0000u);
    l[i] = (short)(__float_as_uint(lf) >> 16);
  }
}

// ---- CSR build ------------------------------------------------------------
__global__ __launch_bounds__(256) void k_deg(const int* __restrict__ dst, int E,
                                             int* __restrict__ cnt){
  int e = blockIdx.x * 256 + threadIdx.x;
  if (e < E) atomicAdd(&cnt[dst[e]], 1);
}

// phase 1: per-block partial sums of cnt
__global__ __launch_bounds__(256) void k_scan_part(const int* __restrict__ cnt,
                                                   int* __restrict__ bsum, int N){
  __shared__ int red[256];
  int t = threadIdx.x;
  int lo = blockIdx.x * SCHUNK + t * 8;
  int s = 0;
#pragma unroll
  for (int k = 0; k < 8; ++k){
    int i = lo + k;
    s += (i < N) ? cnt[i] : 0;
  }
  red[t] = s;
  __syncthreads();
  for (int off = 128; off > 0; off >>= 1){
    if (t < off) red[t] += red[t + off];
    __syncthreads();
  }
  if (t == 0) bsum[blockIdx.x] = red[0];
}

// phase 2: 1-block exclusive scan of block sums (nb <= 1024); also rp[N]=E
__global__ __launch_bounds__(1024) void k_scan_mid(const int* __restrict__ bsum,
                                                   int* __restrict__ boff, int nb,
                                                   int* __restrict__ rp, int N, int E){
  __shared__ int part[1024];
  int t = threadIdx.x;
  part[t] = (t < nb) ? bsum[t] : 0;
  __syncthreads();
  for (int off = 1; off < 1024; off <<= 1){
    int v = (t >= off) ? part[t - off] : 0;
    __syncthreads();
    part[t] += v;
    __syncthreads();
  }
  if (t < nb) boff[t] = (t == 0) ? 0 : part[t - 1];
  if (t == 0) rp[N] = E;
}

// phase 3: local scan + base, write rp; fused dinv = rsqrt(deg+1)
__global__ __launch_bounds__(256) void k_scan_apply(const int* __restrict__ cnt,
                                                    const int* __restrict__ boff,
                                                    int* __restrict__ rp,
                                                    float* __restrict__ dinv, int N){
  __shared__ int tsum[256];
  int t = threadIdx.x;
  int lo = blockIdx.x * SCHUNK + t * 8;
  int v[8];
  int s = 0;
#pragma unroll
  for (int k = 0; k < 8; ++k){
    int i = lo + k;
    v[k] = (i < N) ? cnt[i] : 0;
    s += v[k];
  }
  tsum[t] = s;
  __syncthreads();
  for (int off = 1; off < 256; off <<= 1){
    int u = (t >= off) ? tsum[t - off] : 0;
    __syncthreads();
    tsum[t] += u;
    __syncthreads();
  }
  int base = boff[blockIdx.x] + ((t == 0) ? 0 : tsum[t - 1]);
#pragma unroll
  for (int k = 0; k < 8; ++k){
    int i = lo + k;
    if (i < N){
      rp[i] = base;
      dinv[i] = rsqrtf((float)v[k] + 1.0f);
      base += v[k];
    }
  }
}

// fill: consumes cnt as cursor (atomicSub). edge record = {src, norm} 8B.
__global__ __launch_bounds__(256) void k_fill(const int* __restrict__ src,
                                              const int* __restrict__ dst, int E,
                                              const int* __restrict__ rp,
                                              int* cnt,
                                              const float* __restrict__ dinv,
                                              int2* __restrict__ edges){
  int e = blockIdx.x * 256 + threadIdx.x;
  if (e >= E) return;
  int s = src[e], d = dst[e];
  int pos = rp[d] + atomicSub(&cnt[d], 1) - 1;
  int2 ev;
  ev.x = s;
  ev.y = __float_as_int(dinv[s] * dinv[d]);
  edges[pos] = ev;
}

// ---- weight prep: fp32 -> bf16 hi/lo (round-to-nearest), bias sum ----------
__global__ __launch_bounds__(256) void k_prep_w(const float* __restrict__ Wc,
                                                const float* __restrict__ Wr,
                                                const float* __restrict__ We,
                                                const float* __restrict__ bc,
                                                const float* __restrict__ br,
                                                unsigned short* __restrict__ WcH, unsigned short* __restrict__ WcL,
                                                unsigned short* __restrict__ WrH, unsigned short* __restrict__ WrL,
                                                unsigned short* __restrict__ WeH, unsigned short* __restrict__ WeL,
                                                float* __restrict__ bias_sum){
  int i = blockIdx.x * 256 + threadIdx.x;
  if (i < HD * HD){
    float a = Wc[i]; unsigned short h = f2bf_rn(a); WcH[i] = h; WcL[i] = f2bf_rn(a - bf2f(h));
    float b = Wr[i]; h = f2bf_rn(b); WrH[i] = h; WrL[i] = f2bf_rn(b - bf2f(h));
    float c = We[i]; h = f2bf_rn(c); WeH[i] = h; WeL[i] = f2bf_rn(c - bf2f(h));
  }
  if (i < HD) bias_sum[i] = bc[i] + br[i];
}

// ---- per-layer aggregation: U = A.Xs + (dinv^2-1) Xs  (pull, no atomics) ---
// One wave per node. Half-wave per edge: lanes 0-31 do edges j, j+2,...;
// lanes 32-63 do j+1, j+3,...; each lane gathers float4 (32 lanes * 16B = row).
// 2x unroll => 4 gathers in flight per wave. Cross-half combine via shfl_xor 32.
__global__ __launch_bounds__(256) void k_agg(const float* __restrict__ Xs,
                                             const float* __restrict__ dinv,
                                             const int* __restrict__ rp,
                                             const int2* __restrict__ edges,
                                             float* __restrict__ U,
                                             int N){
  int w = threadIdx.x >> 6;
  int lane = threadIdx.x & 63;
  int half = lane >> 5;
  int hl = lane & 31;
  int node = blockIdx.x * 4 + w;
  if (node >= N) return;

  float4 acc = make_float4(0.f, 0.f, 0.f, 0.f);
  if (half == 0){
    float di = dinv[node];
    float self = di * di - 1.0f;
    float4 sv = ((const float4*)(Xs + (size_t)node * HD))[hl];
    acc.x = self * sv.x; acc.y = self * sv.y;
    acc.z = self * sv.z; acc.w = self * sv.w;
  }

  int b = rp[node], e = rp[node + 1];
  int j = b + half;
  for (; j + 2 < e; j += 4){
    int2 e0 = edges[j];
    int2 e1 = edges[j + 2];
    float w0 = __int_as_float(e0.y);
    float w1 = __int_as_float(e1.y);
    float4 v0 = ((const float4*)(Xs + (size_t)e0.x * HD))[hl];
    float4 v1 = ((const float4*)(Xs + (size_t)e1.x * HD))[hl];
    acc.x = fmaf(w0, v0.x, acc.x); acc.y = fmaf(w0, v0.y, acc.y);
    acc.z = fmaf(w0, v0.z, acc.z); acc.w = fmaf(w0, v0.w, acc.w);
    acc.x = fmaf(w1, v1.x, acc.x); acc.y = fmaf(w1, v1.y, acc.y);
    acc.z = fmaf(w1, v1.z, acc.z); acc.w = fmaf(w1, v1.w, acc.w);
  }
  if (j < e){
    int2 e0 = edges[j];
    float w0 = __int_as_float(e0.y);
    float4 v0 = ((const float4*)(Xs + (size_t)e0.x * HD))[hl];
    acc.x = fmaf(w0, v0.x, acc.x); acc.y = fmaf(w0, v0.y, acc.y);
    acc.z = fmaf(w0, v0.z, acc.z); acc.w = fmaf(w0, v0.w, acc.w);
  }

  acc.x += __shfl_xor(acc.x, 32, 64);
  acc.y += __shfl_xor(acc.y, 32, 64);
  acc.z += __shfl_xor(acc.z, 32, 64);
  acc.w += __shfl_xor(acc.w, 32, 64);
  if (half == 0)
    ((float4*)(U + (size_t)node * HD))[hl] = acc;
}

// ---- fused GEMM: out = relu?( A1 W1^T + A2 W2^T + bias ), optional decode --
__global__ __launch_bounds__(256) void k_gemm(
    const float* A1, const float* A2,
    const unsigned short* __restrict__ W1h, const unsigned short* __restrict__ W1l,
    const unsigned short* __restrict__ W2h, const unsigned short* __restrict__ W2l,
    const float* __restrict__ bias,
    float* outXs,
    const float* __restrict__ Wd, const float* __restrict__ bd,
    float* __restrict__ val,
    int N, int relu, int decode){
  int wid = blockIdx.x * 4 + (threadIdx.x >> 6);
  int row0 = wid * 32;
  if (row0 >= N) return;
  int lane = threadIdx.x & 63;
  int r = lane & 15;
  int kg = lane >> 4;

  f32x4 acc[2][8];
#pragma unroll
  for (int s = 0; s < 2; ++s)
#pragma unroll
    for (int c = 0; c < 8; ++c) acc[s][c] = (f32x4)0.0f;

  const bool two = (A2 != nullptr);

#pragma unroll
  for (int kst = 0; kst < 4; ++kst){
    int k0 = kst * 32 + kg * 8;
    bf16x8 a1h[2], a1l[2], a2h[2], a2l[2];
#pragma unroll
    for (int s = 0; s < 2; ++s){
      size_t ao = (size_t)(row0 + s * 16 + r) * HD + k0;
      split8(A1 + ao, a1h[s], a1l[s]);
      if (two) split8(A2 + ao, a2h[s], a2l[s]);
    }
#pragma unroll
    for (int ct = 0; ct < 8; ++ct){
      size_t bo = (size_t)(ct * 16 + r) * HD + k0;
      bf16x8 b1h = *(const bf16x8*)(W1h + bo);
      bf16x8 b1l = *(const bf16x8*)(W1l + bo);
#pragma unroll
      for (int s = 0; s < 2; ++s){
        acc[s][ct] = __builtin_amdgcn_mfma_f32_16x16x32_bf16(a1h[s], b1h, acc[s][ct], 0, 0, 0);
        acc[s][ct] = __builtin_amdgcn_mfma_f32_16x16x32_bf16(a1h[s], b1l, acc[s][ct], 0, 0, 0);
        acc[s][ct] = __builtin_amdgcn_mfma_f32_16x16x32_bf16(a1l[s], b1h, acc[s][ct], 0, 0, 0);
      }
      if (two){
        bf16x8 b2h = *(const bf16x8*)(W2h + bo);
        bf16x8 b2l = *(const bf16x8*)(W2l + bo);
#pragma unroll
        for (int s = 0; s < 2; ++s){
          acc[s][ct] = __builtin_amdgcn_mfma_f32_16x16x32_bf16(a2h[s], b2h, acc[s][ct], 0, 0, 0);
          acc[s][ct] = __builtin_amdgcn_mfma_f32_16x16x32_bf16(a2h[s], b2l, acc[s][ct], 0, 0, 0);
          acc[s][ct] = __builtin_amdgcn_mfma_f32_16x16x32_bf16(a2l[s], b2h, acc[s][ct], 0, 0, 0);
        }
      }
    }
  }

  // epilogue: C/D layout col = lane&15, row = kg*4 + reg
  float rowp[2][4] = {{0.f,0.f,0.f,0.f},{0.f,0.f,0.f,0.f}};
#pragma unroll
  for (int s = 0; s < 2; ++s){
#pragma unroll
    for (int ct = 0; ct < 8; ++ct){
      int cc = ct * 16 + r;
      float bv = bias[cc];
      float wdv = decode ? Wd[cc] : 0.f;
#pragma unroll
      for (int j = 0; j < 4; ++j){
        float v = acc[s][ct][j] + bv;
        if (relu) v = fmaxf(v, 0.0f);
        if (decode){
          rowp[s][j] += v * wdv;
        } else {
          int rr = row0 + s * 16 + kg * 4 + j;
          outXs[(size_t)rr * HD + cc] = v;
        }
      }
    }
  }
  if (decode){
    float bd0 = bd[0];
#pragma unroll
    for (int s = 0; s < 2; ++s)
#pragma unroll
      for (int j = 0; j < 4; ++j){
        float t = rowp[s][j];
        t += __shfl_xor(t, 1, 64);
        t += __shfl_xor(t, 2, 64);
        t += __shfl_xor(t, 4, 64);
        t += __shfl_xor(t, 8, 64);
        if (r == 0) val[row0 + s * 16 + kg * 4 + j] = t + bd0;
      }
  }
}

// ---- pooling: LDS histogram per block, few global atomics ------------------
#define POOL_CHUNK 1024
__global__ __launch_bounds__(256) void k_pool(const float* __restrict__ val,
                                              const int* __restrict__ batch,
                                              float* __restrict__ out, int N, int G){
  __shared__ float acc[4096];
  int t = threadIdx.x;
  int lo = blockIdx.x * POOL_CHUNK;
  int hi = min(lo + POOL_CHUNK, N);
  if (G <= 4096){
    for (int i = t; i < G; i += 256) acc[i] = 0.f;
    __syncthreads();
    for (int i = lo + t; i < hi; i += 256) atomicAdd(&acc[batch[i]], val[i]);
    __syncthreads();
    for (int i = t; i < G; i += 256){
      float v = acc[i];
      if (v != 0.f) atomicAdd(&out[i], v);
    }
  } else {
    for (int i = lo + t; i < hi; i += 256) atomicAdd(&out[batch[i]], val[i]);
  }
}

// ---- launcher ---------------------------------------------------------------
extern "C" void kernel_launch(void* const* d_in, const int* in_sizes, int n_in,
                              void* d_out, int out_size, void* d_ws, size_t ws_size,
                              hipStream_t stream){
  const float* x      = (const float*)d_in[0];
  const int*   ei     = (const int*)d_in[1];
  const int*   batch  = (const int*)d_in[2];
  const float* W_enc  = (const float*)d_in[3];
  const float* b_enc  = (const float*)d_in[4];
  const float* W_conv = (const float*)d_in[5];
  const float* b_conv = (const float*)d_in[6];
  const float* W_res  = (const float*)d_in[7];
  const float* b_res  = (const float*)d_in[8];
  const float* W_dec  = (const float*)d_in[9];
  const float* b_dec  = (const float*)d_in[10];

  const int N = in_sizes[0] / HD;
  const int E = in_sizes[1] / 2;
  float* out = (float*)d_out;

  char* ws = (char*)d_ws;
  size_t off = 0;
  auto alloc = [&](size_t bytes) -> char* {
    char* p = ws + off;
    off += (bytes + 255) & ~(size_t)255;
    return p;
  };
  int*   cnt   = (int*)  alloc((size_t)N * 4);
  int*   rp    = (int*)  alloc(((size_t)N + 1) * 4);
  float* dinv  = (float*)alloc((size_t)N * 4);
  int*   bsum  = (int*)  alloc(1024 * 4);
  int*   boff  = (int*)  alloc(1024 * 4);
  int2*  edges = (int2*) alloc((size_t)E * 8);
  float* Xs    = (float*)alloc((size_t)N * HD * 4);
  float* U     = (float*)alloc((size_t)N * HD * 4);
  float* val   = (float*)alloc((size_t)N * 4);
  unsigned short* WcH = (unsigned short*)alloc((size_t)HD * HD * 2);
  unsigned short* WcL = (unsigned short*)alloc((size_t)HD * HD * 2);
  unsigned short* WrH = (unsigned short*)alloc((size_t)HD * HD * 2);
  unsigned short* WrL = (unsigned short*)alloc((size_t)HD * HD * 2);
  unsigned short* WeH = (unsigned short*)alloc((size_t)HD * HD * 2);
  unsigned short* WeL = (unsigned short*)alloc((size_t)HD * HD * 2);
  float* bias_sum = (float*)alloc((size_t)HD * 4);

  hipMemsetAsync(cnt, 0, (size_t)N * 4, stream);
  hipMemsetAsync(out, 0, (size_t)out_size * 4, stream);

  const int* src = ei;
  const int* dst = ei + E;

  int nb = (N + SCHUNK - 1) / SCHUNK;

  k_deg       <<<(E + 255) / 256, 256, 0, stream>>>(dst, E, cnt);
  k_scan_part <<<nb, 256, 0, stream>>>(cnt, bsum, N);
  k_scan_mid  <<<1, 1024, 0, stream>>>(bsum, boff, nb, rp, N, E);
  k_scan_apply<<<nb, 256, 0, stream>>>(cnt, boff, rp, dinv, N);
  k_fill      <<<(E + 255) / 256, 256, 0, stream>>>(src, dst, E, rp, cnt, dinv, edges);
  k_prep_w    <<<(HD * HD + 255) / 256, 256, 0, stream>>>(W_conv, W_res, W_enc, b_conv, b_res,
                                                          WcH, WcL, WrH, WrL, WeH, WeL, bias_sum);

  int gemm_blocks = ((N + 31) / 32 + 3) / 4;
  int node_blocks = (N + 3) / 4;

  // encoder: Xs = x @ W_enc^T + b_enc   (no relu)
  k_gemm<<<gemm_blocks, 256, 0, stream>>>(x, nullptr, WeH, WeL, nullptr, nullptr,
                                          b_enc, Xs, nullptr, nullptr, nullptr, N, 0, 0);

  for (int l = 0; l < 5; ++l){
    k_agg<<<node_blocks, 256, 0, stream>>>(Xs, dinv, rp, edges, U, N);
    int last = (l == 4);
    k_gemm<<<gemm_blocks, 256, 0, stream>>>(U, Xs, WcH, WcL, WrH, WrL,
                                            bias_sum, Xs,
                                            W_dec, b_dec, val, N, 1, last);
  }

  k_pool<<<(N + POOL_CHUNK - 1) / POOL_CHUNK, 256, 0, stream>>>(val, batch, out, N, out_size);
}

// Round 4
// 986.534 us; speedup vs baseline: 1.9231x; 1.2355x over previous
//
#include <hip/hip_runtime.h>
#include <hip/hip_bf16.h>
#include <stdint.h>

// GraphCON-GCN on MI355X.
// Algebra: with DT=ALPHA=GAMMA=1, Xs_{l+1} = relu(gcn+res); Y drops out.
// z = (A.Xs) Wc^T + (dinv^2-1) Xs Wc^T + Xs Wr^T + (b_c+b_r)  [self-term folded
// into the GEMM: A1' = U + (dinv^2-1)*Xs computed in-register].
// k_agg gathers an fp16 mirror XsH (256B rows, half the bytes of fp32).
// GEMMs: split-bf16 (hi+lo) MFMA. Decode fused into final GEMM; LDS-hist pool.

#define HD 128
#define SCHUNK 2048   // scan elements per block (256 thr * 8)

typedef __attribute__((ext_vector_type(8))) short bf16x8;
typedef __attribute__((ext_vector_type(4))) float f32x4;
typedef __attribute__((ext_vector_type(8))) float f32x8;
typedef __attribute__((ext_vector_type(4))) _Float16 f16x4;

__device__ __forceinline__ unsigned short f2bf_rn(float f){
  unsigned u = __float_as_uint(f);
  u += 0x7fffu + ((u >> 16) & 1u);
  return (unsigned short)(u >> 16);
}
__device__ __forceinline__ float bf2f(unsigned short h){
  return __uint_as_float(((unsigned)h) << 16);
}

// in-register fp32 -> bf16 hi/lo split (truncating hi; hi+lo ~ 2^-17 rel)
__device__ __forceinline__ void split8v(f32x8 v, bf16x8& h, bf16x8& l){
#pragma unroll
  for (int i = 0; i < 8; ++i){
    unsigned u = __float_as_uint(v[i]);
    h[i] = (short)(u >> 16);
    float lf = v[i] - __uint_as_float(u & 0xffff0000u);
    l[i] = (short)(__float_as_uint(lf) >> 16);
  }
}

// ---- CSR build ------------------------------------------------------------
__global__ __launch_bounds__(256) void k_deg(const int* __restrict__ dst, int E,
                                             int* __restrict__ cnt){
  int e = blockIdx.x * 256 + threadIdx.x;
  if (e < E) atomicAdd(&cnt[dst[e]], 1);
}

__global__ __launch_bounds__(256) void k_scan_part(const int* __restrict__ cnt,
                                                   int* __restrict__ bsum, int N){
  __shared__ int red[256];
  int t = threadIdx.x;
  int lo = blockIdx.x * SCHUNK + t * 8;
  int s = 0;
#pragma unroll
  for (int k = 0; k < 8; ++k){
    int i = lo + k;
    s += (i < N) ? cnt[i] : 0;
  }
  red[t] = s;
  __syncthreads();
  for (int off = 128; off > 0; off >>= 1){
    if (t < off) red[t] += red[t + off];
    __syncthreads();
  }
  if (t == 0) bsum[blockIdx.x] = red[0];
}

__global__ __launch_bounds__(1024) void k_scan_mid(const int* __restrict__ bsum,
                                                   int* __restrict__ boff, int nb,
                                                   int* __restrict__ rp, int N, int E){
  __shared__ int part[1024];
  int t = threadIdx.x;
  part[t] = (t < nb) ? bsum[t] : 0;
  __syncthreads();
  for (int off = 1; off < 1024; off <<= 1){
    int v = (t >= off) ? part[t - off] : 0;
    __syncthreads();
    part[t] += v;
    __syncthreads();
  }
  if (t < nb) boff[t] = (t == 0) ? 0 : part[t - 1];
  if (t == 0) rp[N] = E;
}

__global__ __launch_bounds__(256) void k_scan_apply(const int* __restrict__ cnt,
                                                    const int* __restrict__ boff,
                                                    int* __restrict__ rp,
                                                    float* __restrict__ dinv, int N){
  __shared__ int tsum[256];
  int t = threadIdx.x;
  int lo = blockIdx.x * SCHUNK + t * 8;
  int v[8];
  int s = 0;
#pragma unroll
  for (int k = 0; k < 8; ++k){
    int i = lo + k;
    v[k] = (i < N) ? cnt[i] : 0;
    s += v[k];
  }
  tsum[t] = s;
  __syncthreads();
  for (int off = 1; off < 256; off <<= 1){
    int u = (t >= off) ? tsum[t - off] : 0;
    __syncthreads();
    tsum[t] += u;
    __syncthreads();
  }
  int base = boff[blockIdx.x] + ((t == 0) ? 0 : tsum[t - 1]);
#pragma unroll
  for (int k = 0; k < 8; ++k){
    int i = lo + k;
    if (i < N){
      rp[i] = base;
      dinv[i] = rsqrtf((float)v[k] + 1.0f);
      base += v[k];
    }
  }
}

// fill: consumes cnt as cursor (atomicSub). edge record = {src, norm} 8B.
__global__ __launch_bounds__(256) void k_fill(const int* __restrict__ src,
                                              const int* __restrict__ dst, int E,
                                              const int* __restrict__ rp,
                                              int* cnt,
                                              const float* __restrict__ dinv,
                                              int2* __restrict__ edges){
  int e = blockIdx.x * 256 + threadIdx.x;
  if (e >= E) return;
  int s = src[e], d = dst[e];
  int pos = rp[d] + atomicSub(&cnt[d], 1) - 1;
  int2 ev;
  ev.x = s;
  ev.y = __float_as_int(dinv[s] * dinv[d]);
  edges[pos] = ev;
}

// ---- weight prep: fp32 -> bf16 hi/lo (round-to-nearest), bias sum ----------
__global__ __launch_bounds__(256) void k_prep_w(const float* __restrict__ Wc,
                                                const float* __restrict__ Wr,
                                                const float* __restrict__ We,
                                                const float* __restrict__ bc,
                                                const float* __restrict__ br,
                                                unsigned short* __restrict__ WcH, unsigned short* __restrict__ WcL,
                                                unsigned short* __restrict__ WrH, unsigned short* __restrict__ WrL,
                                                unsigned short* __restrict__ WeH, unsigned short* __restrict__ WeL,
                                                float* __restrict__ bias_sum){
  int i = blockIdx.x * 256 + threadIdx.x;
  if (i < HD * HD){
    float a = Wc[i]; unsigned short h = f2bf_rn(a); WcH[i] = h; WcL[i] = f2bf_rn(a - bf2f(h));
    float b = Wr[i]; h = f2bf_rn(b); WrH[i] = h; WrL[i] = f2bf_rn(b - bf2f(h));
    float c = We[i]; h = f2bf_rn(c); WeH[i] = h; WeL[i] = f2bf_rn(c - bf2f(h));
  }
  if (i < HD) bias_sum[i] = bc[i] + br[i];
}

// ---- per-layer aggregation: U = A.XsH  (fp16 gathers, no self term) --------
// One wave per node. Half-wave per edge; each lane gathers f16x4 (8B);
// 32 lanes * 8B = 256B row. 2x unroll => 4 gathers in flight per wave.
__global__ __launch_bounds__(256) void k_agg(const _Float16* __restrict__ XsH,
                                             const int* __restrict__ rp,
                                             const int2* __restrict__ edges,
                                             float* __restrict__ U,
                                             int N){
  int w = threadIdx.x >> 6;
  int lane = threadIdx.x & 63;
  int half = lane >> 5;
  int hl = lane & 31;
  int node = blockIdx.x * 4 + w;
  if (node >= N) return;

  float4 acc = make_float4(0.f, 0.f, 0.f, 0.f);

  int b = rp[node], e = rp[node + 1];
  int j = b + half;
  for (; j + 2 < e; j += 4){
    int2 e0 = edges[j];
    int2 e1 = edges[j + 2];
    float w0 = __int_as_float(e0.y);
    float w1 = __int_as_float(e1.y);
    f16x4 v0 = ((const f16x4*)(XsH + (size_t)e0.x * HD))[hl];
    f16x4 v1 = ((const f16x4*)(XsH + (size_t)e1.x * HD))[hl];
    acc.x = fmaf(w0, (float)v0[0], acc.x); acc.y = fmaf(w0, (float)v0[1], acc.y);
    acc.z = fmaf(w0, (float)v0[2], acc.z); acc.w = fmaf(w0, (float)v0[3], acc.w);
    acc.x = fmaf(w1, (float)v1[0], acc.x); acc.y = fmaf(w1, (float)v1[1], acc.y);
    acc.z = fmaf(w1, (float)v1[2], acc.z); acc.w = fmaf(w1, (float)v1[3], acc.w);
  }
  if (j < e){
    int2 e0 = edges[j];
    float w0 = __int_as_float(e0.y);
    f16x4 v0 = ((const f16x4*)(XsH + (size_t)e0.x * HD))[hl];
    acc.x = fmaf(w0, (float)v0[0], acc.x); acc.y = fmaf(w0, (float)v0[1], acc.y);
    acc.z = fmaf(w0, (float)v0[2], acc.z); acc.w = fmaf(w0, (float)v0[3], acc.w);
  }

  acc.x += __shfl_xor(acc.x, 32, 64);
  acc.y += __shfl_xor(acc.y, 32, 64);
  acc.z += __shfl_xor(acc.z, 32, 64);
  acc.w += __shfl_xor(acc.w, 32, 64);
  if (half == 0){
    float2 lo2; lo2.x = acc.x; lo2.y = acc.y;
    float2 hi2; hi2.x = acc.z; hi2.y = acc.w;
    ((float2*)(U + (size_t)node * HD))[hl * 2]     = lo2;
    ((float2*)(U + (size_t)node * HD))[hl * 2 + 1] = hi2;
  }
}

// ---- fused GEMM ------------------------------------------------------------
// two=false: out = A1 We^T + bias (encoder).
// two=true:  A1' = A1 + (dinv[row]^2-1)*A2 in-register;
//            out = relu(A1' Wc^T + A2 Wr^T + bias). Writes Xs fp32 + XsH fp16.
// decode: skip stores, val[row] = dot(out_row, Wd) + bd[0].
__global__ __launch_bounds__(256) void k_gemm(
    const float* A1, const float* A2,
    const unsigned short* __restrict__ W1h, const unsigned short* __restrict__ W1l,
    const unsigned short* __restrict__ W2h, const unsigned short* __restrict__ W2l,
    const float* __restrict__ dinvp,
    const float* __restrict__ bias,
    float* outXs, _Float16* outXsH,
    const float* __restrict__ Wd, const float* __restrict__ bd,
    float* __restrict__ val,
    int N, int relu, int decode){
  int wid = blockIdx.x * 4 + (threadIdx.x >> 6);
  int row0 = wid * 32;
  if (row0 >= N) return;
  int lane = threadIdx.x & 63;
  int r = lane & 15;
  int kg = lane >> 4;

  f32x4 acc[2][8];
#pragma unroll
  for (int s = 0; s < 2; ++s)
#pragma unroll
    for (int c = 0; c < 8; ++c) acc[s][c] = (f32x4)0.0f;

  const bool two = (A2 != nullptr);
  float sr[2] = {0.f, 0.f};
  if (two){
#pragma unroll
    for (int s = 0; s < 2; ++s){
      float d = dinvp[row0 + s * 16 + r];
      sr[s] = d * d - 1.0f;
    }
  }

#pragma unroll
  for (int kst = 0; kst < 4; ++kst){
    int k0 = kst * 32 + kg * 8;
    bf16x8 a1h[2], a1l[2], a2h[2], a2l[2];
#pragma unroll
    for (int s = 0; s < 2; ++s){
      size_t ao = (size_t)(row0 + s * 16 + r) * HD + k0;
      f32x8 u = *(const f32x8*)(A1 + ao);
      if (two){
        f32x8 xv = *(const f32x8*)(A2 + ao);
        f32x8 comb;
#pragma unroll
        for (int i = 0; i < 8; ++i) comb[i] = fmaf(sr[s], xv[i], u[i]);
        split8v(comb, a1h[s], a1l[s]);
        split8v(xv,   a2h[s], a2l[s]);
      } else {
        split8v(u, a1h[s], a1l[s]);
      }
    }
#pragma unroll
    for (int ct = 0; ct < 8; ++ct){
      size_t bo = (size_t)(ct * 16 + r) * HD + k0;
      bf16x8 b1h = *(const bf16x8*)(W1h + bo);
      bf16x8 b1l = *(const bf16x8*)(W1l + bo);
#pragma unroll
      for (int s = 0; s < 2; ++s){
        acc[s][ct] = __builtin_amdgcn_mfma_f32_16x16x32_bf16(a1h[s], b1h, acc[s][ct], 0, 0, 0);
        acc[s][ct] = __builtin_amdgcn_mfma_f32_16x16x32_bf16(a1h[s], b1l, acc[s][ct], 0, 0, 0);
        acc[s][ct] = __builtin_amdgcn_mfma_f32_16x16x32_bf16(a1l[s], b1h, acc[s][ct], 0, 0, 0);
      }
      if (two){
        bf16x8 b2h = *(const bf16x8*)(W2h + bo);
        bf16x8 b2l = *(const bf16x8*)(W2l + bo);
#pragma unroll
        for (int s = 0; s < 2; ++s){
          acc[s][ct] = __builtin_amdgcn_mfma_f32_16x16x32_bf16(a2h[s], b2h, acc[s][ct], 0, 0, 0);
          acc[s][ct] = __builtin_amdgcn_mfma_f32_16x16x32_bf16(a2h[s], b2l, acc[s][ct], 0, 0, 0);
          acc[s][ct] = __builtin_amdgcn_mfma_f32_16x16x32_bf16(a2l[s], b2h, acc[s][ct], 0, 0, 0);
        }
      }
    }
  }

  // epilogue: C/D layout col = lane&15, row = kg*4 + reg
  float rowp[2][4] = {{0.f,0.f,0.f,0.f},{0.f,0.f,0.f,0.f}};
#pragma unroll
  for (int s = 0; s < 2; ++s){
#pragma unroll
    for (int ct = 0; ct < 8; ++ct){
      int cc = ct * 16 + r;
      float bv = bias[cc];
      float wdv = decode ? Wd[cc] : 0.f;
#pragma unroll
      for (int j = 0; j < 4; ++j){
        float v = acc[s][ct][j] + bv;
        if (relu) v = fmaxf(v, 0.0f);
        if (decode){
          rowp[s][j] += v * wdv;
        } else {
          int rr = row0 + s * 16 + kg * 4 + j;
          outXs[(size_t)rr * HD + cc] = v;
          outXsH[(size_t)rr * HD + cc] = (_Float16)v;
        }
      }
    }
  }
  if (decode){
    float bd0 = bd[0];
#pragma unroll
    for (int s = 0; s < 2; ++s)
#pragma unroll
      for (int j = 0; j < 4; ++j){
        float t = rowp[s][j];
        t += __shfl_xor(t, 1, 64);
        t += __shfl_xor(t, 2, 64);
        t += __shfl_xor(t, 4, 64);
        t += __shfl_xor(t, 8, 64);
        if (r == 0) val[row0 + s * 16 + kg * 4 + j] = t + bd0;
      }
  }
}

// ---- pooling: LDS histogram per block, few global atomics ------------------
#define POOL_CHUNK 1024
__global__ __launch_bounds__(256) void k_pool(const float* __restrict__ val,
                                              const int* __restrict__ batch,
                                              float* __restrict__ out, int N, int G){
  __shared__ float acc[4096];
  int t = threadIdx.x;
  int lo = blockIdx.x * POOL_CHUNK;
  int hi = min(lo + POOL_CHUNK, N);
  if (G <= 4096){
    for (int i = t; i < G; i += 256) acc[i] = 0.f;
    __syncthreads();
    for (int i = lo + t; i < hi; i += 256) atomicAdd(&acc[batch[i]], val[i]);
    __syncthreads();
    for (int i = t; i < G; i += 256){
      float v = acc[i];
      if (v != 0.f) atomicAdd(&out[i], v);
    }
  } else {
    for (int i = lo + t; i < hi; i += 256) atomicAdd(&out[batch[i]], val[i]);
  }
}

// ---- launcher ---------------------------------------------------------------
extern "C" void kernel_launch(void* const* d_in, const int* in_sizes, int n_in,
                              void* d_out, int out_size, void* d_ws, size_t ws_size,
                              hipStream_t stream){
  const float* x      = (const float*)d_in[0];
  const int*   ei     = (const int*)d_in[1];
  const int*   batch  = (const int*)d_in[2];
  const float* W_enc  = (const float*)d_in[3];
  const float* b_enc  = (const float*)d_in[4];
  const float* W_conv = (const float*)d_in[5];
  const float* b_conv = (const float*)d_in[6];
  const float* W_res  = (const float*)d_in[7];
  const float* b_res  = (const float*)d_in[8];
  const float* W_dec  = (const float*)d_in[9];
  const float* b_dec  = (const float*)d_in[10];

  const int N = in_sizes[0] / HD;
  const int E = in_sizes[1] / 2;
  float* out = (float*)d_out;

  char* ws = (char*)d_ws;
  size_t off = 0;
  auto alloc = [&](size_t bytes) -> char* {
    char* p = ws + off;
    off += (bytes + 255) & ~(size_t)255;
    return p;
  };
  int*   cnt   = (int*)  alloc((size_t)N * 4);
  int*   rp    = (int*)  alloc(((size_t)N + 1) * 4);
  float* dinv  = (float*)alloc((size_t)N * 4);
  int*   bsum  = (int*)  alloc(1024 * 4);
  int*   boff  = (int*)  alloc(1024 * 4);
  int2*  edges = (int2*) alloc((size_t)E * 8);
  float* Xs    = (float*)alloc((size_t)N * HD * 4);
  _Float16* XsH= (_Float16*)alloc((size_t)N * HD * 2);
  float* U     = (float*)alloc((size_t)N * HD * 4);
  float* val   = (float*)alloc((size_t)N * 4);
  unsigned short* WcH = (unsigned short*)alloc((size_t)HD * HD * 2);
  unsigned short* WcL = (unsigned short*)alloc((size_t)HD * HD * 2);
  unsigned short* WrH = (unsigned short*)alloc((size_t)HD * HD * 2);
  unsigned short* WrL = (unsigned short*)alloc((size_t)HD * HD * 2);
  unsigned short* WeH = (unsigned short*)alloc((size_t)HD * HD * 2);
  unsigned short* WeL = (unsigned short*)alloc((size_t)HD * HD * 2);
  float* bias_sum = (float*)alloc((size_t)HD * 4);

  hipMemsetAsync(cnt, 0, (size_t)N * 4, stream);
  hipMemsetAsync(out, 0, (size_t)out_size * 4, stream);

  const int* src = ei;
  const int* dst = ei + E;

  int nb = (N + SCHUNK - 1) / SCHUNK;

  k_deg       <<<(E + 255) / 256, 256, 0, stream>>>(dst, E, cnt);
  k_scan_part <<<nb, 256, 0, stream>>>(cnt, bsum, N);
  k_scan_mid  <<<1, 1024, 0, stream>>>(bsum, boff, nb, rp, N, E);
  k_scan_apply<<<nb, 256, 0, stream>>>(cnt, boff, rp, dinv, N);
  k_fill      <<<(E + 255) / 256, 256, 0, stream>>>(src, dst, E, rp, cnt, dinv, edges);
  k_prep_w    <<<(HD * HD + 255) / 256, 256, 0, stream>>>(W_conv, W_res, W_enc, b_conv, b_res,
                                                          WcH, WcL, WrH, WrL, WeH, WeL, bias_sum);

  int gemm_blocks = ((N + 31) / 32 + 3) / 4;
  int node_blocks = (N + 3) / 4;

  // encoder: Xs = x @ W_enc^T + b_enc   (no relu, no self-fold)
  k_gemm<<<gemm_blocks, 256, 0, stream>>>(x, nullptr, WeH, WeL, nullptr, nullptr,
                                          nullptr, b_enc, Xs, XsH,
                                          nullptr, nullptr, nullptr, N, 0, 0);

  for (int l = 0; l < 5; ++l){
    k_agg<<<node_blocks, 256, 0, stream>>>(XsH, rp, edges, U, N);
    int last = (l == 4);
    k_gemm<<<gemm_blocks, 256, 0, stream>>>(U, Xs, WcH, WcL, WrH, WrL,
                                            dinv, bias_sum, Xs, XsH,
                                            W_dec, b_dec, val, N, 1, last);
  }

  k_pool<<<(N + POOL_CHUNK - 1) / POOL_CHUNK, 256, 0, stream>>>(val, batch, out, N, out_size);
}

// Round 5
// 788.956 us; speedup vs baseline: 2.4047x; 1.2504x over previous
//
#include <hip/hip_runtime.h>
#include <hip/hip_bf16.h>
#include <stdint.h>

// GraphCON-GCN on MI355X.
// Algebra: with DT=ALPHA=GAMMA=1, Xs_{l+1} = relu(gcn+res); Y drops out.
// z = (A.Xs) Wc^T + (dinv^2-1) Xs Wc^T + Xs Wr^T + (b_c+b_r)  [self-term folded
// into the GEMM in-register]. State Xs kept fp16 only (XsH); agg gathers fp16;
// GEMM is pure fp16 MFMA (16x16x32_f16, fp32 accum). Decode fused into final
// GEMM epilogue; pooling via LDS histogram.

#define HD 128
#define SCHUNK 2048   // scan elements per block (256 thr * 8)

typedef __attribute__((ext_vector_type(4))) float f32x4;
typedef __attribute__((ext_vector_type(8))) float f32x8;
typedef __attribute__((ext_vector_type(8))) _Float16 f16x8;

// ---- CSR build ------------------------------------------------------------
__global__ __launch_bounds__(256) void k_deg(const int* __restrict__ dst, int E,
                                             int* __restrict__ cnt){
  int e = blockIdx.x * 256 + threadIdx.x;
  if (e < E) atomicAdd(&cnt[dst[e]], 1);
}

__global__ __launch_bounds__(256) void k_scan_part(const int* __restrict__ cnt,
                                                   int* __restrict__ bsum, int N){
  __shared__ int red[256];
  int t = threadIdx.x;
  int lo = blockIdx.x * SCHUNK + t * 8;
  int s = 0;
#pragma unroll
  for (int k = 0; k < 8; ++k){
    int i = lo + k;
    s += (i < N) ? cnt[i] : 0;
  }
  red[t] = s;
  __syncthreads();
  for (int off = 128; off > 0; off >>= 1){
    if (t < off) red[t] += red[t + off];
    __syncthreads();
  }
  if (t == 0) bsum[blockIdx.x] = red[0];
}

__global__ __launch_bounds__(1024) void k_scan_mid(const int* __restrict__ bsum,
                                                   int* __restrict__ boff, int nb,
                                                   int* __restrict__ rp, int N, int E){
  __shared__ int part[1024];
  int t = threadIdx.x;
  part[t] = (t < nb) ? bsum[t] : 0;
  __syncthreads();
  for (int off = 1; off < 1024; off <<= 1){
    int v = (t >= off) ? part[t - off] : 0;
    __syncthreads();
    part[t] += v;
    __syncthreads();
  }
  if (t < nb) boff[t] = (t == 0) ? 0 : part[t - 1];
  if (t == 0) rp[N] = E;
}

__global__ __launch_bounds__(256) void k_scan_apply(const int* __restrict__ cnt,
                                                    const int* __restrict__ boff,
                                                    int* __restrict__ rp,
                                                    float* __restrict__ dinv, int N){
  __shared__ int tsum[256];
  int t = threadIdx.x;
  int lo = blockIdx.x * SCHUNK + t * 8;
  int v[8];
  int s = 0;
#pragma unroll
  for (int k = 0; k < 8; ++k){
    int i = lo + k;
    v[k] = (i < N) ? cnt[i] : 0;
    s += v[k];
  }
  tsum[t] = s;
  __syncthreads();
  for (int off = 1; off < 256; off <<= 1){
    int u = (t >= off) ? tsum[t - off] : 0;
    __syncthreads();
    tsum[t] += u;
    __syncthreads();
  }
  int base = boff[blockIdx.x] + ((t == 0) ? 0 : tsum[t - 1]);
#pragma unroll
  for (int k = 0; k < 8; ++k){
    int i = lo + k;
    if (i < N){
      rp[i] = base;
      dinv[i] = rsqrtf((float)v[k] + 1.0f);
      base += v[k];
    }
  }
}

// fill: consumes cnt as cursor (atomicSub). edge record = {src, norm} 8B.
__global__ __launch_bounds__(256) void k_fill(const int* __restrict__ src,
                                              const int* __restrict__ dst, int E,
                                              const int* __restrict__ rp,
                                              int* cnt,
                                              const float* __restrict__ dinv,
                                              int2* __restrict__ edges){
  int e = blockIdx.x * 256 + threadIdx.x;
  if (e >= E) return;
  int s = src[e], d = dst[e];
  int pos = rp[d] + atomicSub(&cnt[d], 1) - 1;
  int2 ev;
  ev.x = s;
  ev.y = __float_as_int(dinv[s] * dinv[d]);
  edges[pos] = ev;
}

// ---- weight prep: fp32 -> fp16 (RTN), bias sum -----------------------------
__global__ __launch_bounds__(256) void k_prep_w(const float* __restrict__ Wc,
                                                const float* __restrict__ Wr,
                                                const float* __restrict__ We,
                                                const float* __restrict__ bc,
                                                const float* __restrict__ br,
                                                _Float16* __restrict__ WcF,
                                                _Float16* __restrict__ WrF,
                                                _Float16* __restrict__ WeF,
                                                float* __restrict__ bias_sum){
  int i = blockIdx.x * 256 + threadIdx.x;
  if (i < HD * HD){
    WcF[i] = (_Float16)Wc[i];
    WrF[i] = (_Float16)Wr[i];
    WeF[i] = (_Float16)We[i];
  }
  if (i < HD) bias_sum[i] = bc[i] + br[i];
}

// ---- per-layer aggregation: U = A.XsH  (fp16 gathers, no self term) --------
// One wave per node. Quarter-wave per edge: lane group q = lane>>4 handles
// edges b+q, b+q+4, ...; each lane gathers f16x8 (16B); 16 lanes * 16B = 256B
// row. 2x unroll => 8 gathers in flight per wave. shfl_xor(16,32) combine.
__global__ __launch_bounds__(256) void k_agg(const _Float16* __restrict__ XsH,
                                             const int* __restrict__ rp,
                                             const int2* __restrict__ edges,
                                             float* __restrict__ U,
                                             int N){
  int w = threadIdx.x >> 6;
  int lane = threadIdx.x & 63;
  int q = lane >> 4;       // edge slot 0..3
  int ql = lane & 15;      // channel group: cols ql*8 .. ql*8+7
  int node = blockIdx.x * 4 + w;
  if (node >= N) return;

  float acc[8];
#pragma unroll
  for (int i = 0; i < 8; ++i) acc[i] = 0.f;

  int b = rp[node], e = rp[node + 1];
  int j = b + q;
  for (; j + 4 < e; j += 8){
    int2 e0 = edges[j];
    int2 e1 = edges[j + 4];
    float w0 = __int_as_float(e0.y);
    float w1 = __int_as_float(e1.y);
    f16x8 v0 = ((const f16x8*)(XsH + (size_t)e0.x * HD))[ql];
    f16x8 v1 = ((const f16x8*)(XsH + (size_t)e1.x * HD))[ql];
#pragma unroll
    for (int i = 0; i < 8; ++i) acc[i] = fmaf(w0, (float)v0[i], acc[i]);
#pragma unroll
    for (int i = 0; i < 8; ++i) acc[i] = fmaf(w1, (float)v1[i], acc[i]);
  }
  if (j < e){
    int2 e0 = edges[j];
    float w0 = __int_as_float(e0.y);
    f16x8 v0 = ((const f16x8*)(XsH + (size_t)e0.x * HD))[ql];
#pragma unroll
    for (int i = 0; i < 8; ++i) acc[i] = fmaf(w0, (float)v0[i], acc[i]);
  }

#pragma unroll
  for (int i = 0; i < 8; ++i){
    acc[i] += __shfl_xor(acc[i], 16, 64);
    acc[i] += __shfl_xor(acc[i], 32, 64);
  }
  if (q == 0){
    float4 lo4 = make_float4(acc[0], acc[1], acc[2], acc[3]);
    float4 hi4 = make_float4(acc[4], acc[5], acc[6], acc[7]);
    float* urow = U + (size_t)node * HD + ql * 8;
    *(float4*)urow = lo4;
    *(float4*)(urow + 4) = hi4;
  }
}

// ---- fused fp16 GEMM -------------------------------------------------------
// two=false: out = cvt16(A1f) We^T + bias (encoder; A1f fp32).
// two=true:  A1' = U + (dinv[row]^2-1)*XsH (in-register, fp32->fp16);
//            out = relu(A1' Wc^T + XsH Wr^T + bias). Writes XsH fp16.
// decode: skip stores, val[row] = dot(out_row, Wd) + bd[0].
__global__ __launch_bounds__(256) void k_gemm(
    const float* __restrict__ A1f,            // U (fp32) or x (fp32)
    const _Float16* A2h,                      // XsH (aliases outXsH) or null
    const _Float16* __restrict__ W1,          // WcF or WeF
    const _Float16* __restrict__ W2,          // WrF or null
    const float* __restrict__ dinvp,
    const float* __restrict__ bias,
    _Float16* outXsH,
    const float* __restrict__ Wd, const float* __restrict__ bd,
    float* __restrict__ val,
    int N, int relu, int decode){
  int wid = blockIdx.x * 4 + (threadIdx.x >> 6);
  int row0 = wid * 32;
  if (row0 >= N) return;
  int lane = threadIdx.x & 63;
  int r = lane & 15;
  int kg = lane >> 4;

  f32x4 acc[2][8];
#pragma unroll
  for (int s = 0; s < 2; ++s)
#pragma unroll
    for (int c = 0; c < 8; ++c) acc[s][c] = (f32x4)0.0f;

  const bool two = (A2h != nullptr);
  float sr[2] = {0.f, 0.f};
  if (two){
#pragma unroll
    for (int s = 0; s < 2; ++s){
      float d = dinvp[row0 + s * 16 + r];
      sr[s] = d * d - 1.0f;
    }
  }

#pragma unroll
  for (int kst = 0; kst < 4; ++kst){
    int k0 = kst * 32 + kg * 8;
    f16x8 a1[2], a2[2];
#pragma unroll
    for (int s = 0; s < 2; ++s){
      size_t ao = (size_t)(row0 + s * 16 + r) * HD + k0;
      f32x8 u = *(const f32x8*)(A1f + ao);
      if (two){
        f16x8 xv = *(const f16x8*)(A2h + ao);
        a2[s] = xv;
#pragma unroll
        for (int i = 0; i < 8; ++i)
          a1[s][i] = (_Float16)fmaf(sr[s], (float)xv[i], u[i]);
      } else {
#pragma unroll
        for (int i = 0; i < 8; ++i) a1[s][i] = (_Float16)u[i];
      }
    }
#pragma unroll
    for (int ct = 0; ct < 8; ++ct){
      size_t bo = (size_t)(ct * 16 + r) * HD + k0;
      f16x8 b1 = *(const f16x8*)(W1 + bo);
#pragma unroll
      for (int s = 0; s < 2; ++s)
        acc[s][ct] = __builtin_amdgcn_mfma_f32_16x16x32_f16(a1[s], b1, acc[s][ct], 0, 0, 0);
      if (two){
        f16x8 b2 = *(const f16x8*)(W2 + bo);
#pragma unroll
        for (int s = 0; s < 2; ++s)
          acc[s][ct] = __builtin_amdgcn_mfma_f32_16x16x32_f16(a2[s], b2, acc[s][ct], 0, 0, 0);
      }
    }
  }

  // epilogue: C/D layout col = lane&15, row = kg*4 + reg
  float rowp[2][4] = {{0.f,0.f,0.f,0.f},{0.f,0.f,0.f,0.f}};
#pragma unroll
  for (int s = 0; s < 2; ++s){
#pragma unroll
    for (int ct = 0; ct < 8; ++ct){
      int cc = ct * 16 + r;
      float bv = bias[cc];
      float wdv = decode ? Wd[cc] : 0.f;
#pragma unroll
      for (int j = 0; j < 4; ++j){
        float v = acc[s][ct][j] + bv;
        if (relu) v = fmaxf(v, 0.0f);
        if (decode){
          rowp[s][j] += v * wdv;
        } else {
          int rr = row0 + s * 16 + kg * 4 + j;
          outXsH[(size_t)rr * HD + cc] = (_Float16)v;
        }
      }
    }
  }
  if (decode){
    float bd0 = bd[0];
#pragma unroll
    for (int s = 0; s < 2; ++s)
#pragma unroll
      for (int j = 0; j < 4; ++j){
        float t = rowp[s][j];
        t += __shfl_xor(t, 1, 64);
        t += __shfl_xor(t, 2, 64);
        t += __shfl_xor(t, 4, 64);
        t += __shfl_xor(t, 8, 64);
        if (r == 0) val[row0 + s * 16 + kg * 4 + j] = t + bd0;
      }
  }
}

// ---- pooling: LDS histogram per block, few global atomics ------------------
#define POOL_CHUNK 1024
__global__ __launch_bounds__(256) void k_pool(const float* __restrict__ val,
                                              const int* __restrict__ batch,
                                              float* __restrict__ out, int N, int G){
  __shared__ float acc[4096];
  int t = threadIdx.x;
  int lo = blockIdx.x * POOL_CHUNK;
  int hi = min(lo + POOL_CHUNK, N);
  if (G <= 4096){
    for (int i = t; i < G; i += 256) acc[i] = 0.f;
    __syncthreads();
    for (int i = lo + t; i < hi; i += 256) atomicAdd(&acc[batch[i]], val[i]);
    __syncthreads();
    for (int i = t; i < G; i += 256){
      float v = acc[i];
      if (v != 0.f) atomicAdd(&out[i], v);
    }
  } else {
    for (int i = lo + t; i < hi; i += 256) atomicAdd(&out[batch[i]], val[i]);
  }
}

// ---- launcher ---------------------------------------------------------------
extern "C" void kernel_launch(void* const* d_in, const int* in_sizes, int n_in,
                              void* d_out, int out_size, void* d_ws, size_t ws_size,
                              hipStream_t stream){
  const float* x      = (const float*)d_in[0];
  const int*   ei     = (const int*)d_in[1];
  const int*   batch  = (const int*)d_in[2];
  const float* W_enc  = (const float*)d_in[3];
  const float* b_enc  = (const float*)d_in[4];
  const float* W_conv = (const float*)d_in[5];
  const float* b_conv = (const float*)d_in[6];
  const float* W_res  = (const float*)d_in[7];
  const float* b_res  = (const float*)d_in[8];
  const float* W_dec  = (const float*)d_in[9];
  const float* b_dec  = (const float*)d_in[10];

  const int N = in_sizes[0] / HD;
  const int E = in_sizes[1] / 2;
  float* out = (float*)d_out;

  char* ws = (char*)d_ws;
  size_t off = 0;
  auto alloc = [&](size_t bytes) -> char* {
    char* p = ws + off;
    off += (bytes + 255) & ~(size_t)255;
    return p;
  };
  int*   cnt   = (int*)  alloc((size_t)N * 4);
  int*   rp    = (int*)  alloc(((size_t)N + 1) * 4);
  float* dinv  = (float*)alloc((size_t)N * 4);
  int*   bsum  = (int*)  alloc(1024 * 4);
  int*   boff  = (int*)  alloc(1024 * 4);
  int2*  edges = (int2*) alloc((size_t)E * 8);
  _Float16* XsH= (_Float16*)alloc((size_t)N * HD * 2);
  float* U     = (float*)alloc((size_t)N * HD * 4);
  float* val   = (float*)alloc((size_t)N * 4);
  _Float16* WcF = (_Float16*)alloc((size_t)HD * HD * 2);
  _Float16* WrF = (_Float16*)alloc((size_t)HD * HD * 2);
  _Float16* WeF = (_Float16*)alloc((size_t)HD * HD * 2);
  float* bias_sum = (float*)alloc((size_t)HD * 4);

  hipMemsetAsync(cnt, 0, (size_t)N * 4, stream);
  hipMemsetAsync(out, 0, (size_t)out_size * 4, stream);

  const int* src = ei;
  const int* dst = ei + E;

  int nb = (N + SCHUNK - 1) / SCHUNK;

  k_deg       <<<(E + 255) / 256, 256, 0, stream>>>(dst, E, cnt);
  k_scan_part <<<nb, 256, 0, stream>>>(cnt, bsum, N);
  k_scan_mid  <<<1, 1024, 0, stream>>>(bsum, boff, nb, rp, N, E);
  k_scan_apply<<<nb, 256, 0, stream>>>(cnt, boff, rp, dinv, N);
  k_fill      <<<(E + 255) / 256, 256, 0, stream>>>(src, dst, E, rp, cnt, dinv, edges);
  k_prep_w    <<<(HD * HD + 255) / 256, 256, 0, stream>>>(W_conv, W_res, W_enc, b_conv, b_res,
                                                          WcF, WrF, WeF, bias_sum);

  int gemm_blocks = ((N + 31) / 32 + 3) / 4;
  int node_blocks = (N + 3) / 4;

  // encoder: XsH = fp16(x @ W_enc^T + b_enc)   (no relu, no self-fold)
  k_gemm<<<gemm_blocks, 256, 0, stream>>>(x, nullptr, WeF, nullptr,
                                          nullptr, b_enc, XsH,
                                          nullptr, nullptr, nullptr, N, 0, 0);

  for (int l = 0; l < 5; ++l){
    k_agg<<<node_blocks, 256, 0, stream>>>(XsH, rp, edges, U, N);
    int last = (l == 4);
    k_gemm<<<gemm_blocks, 256, 0, stream>>>(U, XsH, WcF, WrF,
                                            dinv, bias_sum, XsH,
                                            W_dec, b_dec, val, N, 1, last);
  }

  k_pool<<<(N + POOL_CHUNK - 1) / POOL_CHUNK, 256, 0, stream>>>(val, batch, out, N, out_size);
}

// Round 6
// 644.499 us; speedup vs baseline: 2.9436x; 1.2241x over previous
//
#include <hip/hip_runtime.h>
#include <hip/hip_bf16.h>
#include <stdint.h>

// GraphCON-GCN on MI355X.
// Algebra: with DT=ALPHA=GAMMA=1, Xs_{l+1} = relu(gcn+res); Y drops out.
// z = (A.Xs) Wc^T + (dinv^2-1) Xs Wc^T + Xs Wr^T + (b_c+b_r)  [self-term folded
// into the GEMM in-register]. State fp16 (XsH); agg gathers fp16, U fp16.
// Edge record = 4B: (deg+1)<<18 | src; dinv[src]=rsqrt(deg+1) recomputed
// bit-exactly in agg, dinv[dst] factored out of the edge loop.
// GEMM: fp16 MFMA (16x16x32_f16, fp32 accum), weights LDS-staged (swizzled).
// Decode fused into final GEMM; pooling via LDS histogram.

#define HD 128
#define SCHUNK 2048   // scan elements per block (256 thr * 8)

typedef __attribute__((ext_vector_type(4))) float f32x4;
typedef __attribute__((ext_vector_type(8))) float f32x8;
typedef __attribute__((ext_vector_type(8))) _Float16 f16x8;

// ---- CSR build ------------------------------------------------------------
__global__ __launch_bounds__(256) void k_deg(const int* __restrict__ dst, int E,
                                             int* __restrict__ cnt){
  int e = blockIdx.x * 256 + threadIdx.x;
  if (e < E) atomicAdd(&cnt[dst[e]], 1);
}

__global__ __launch_bounds__(256) void k_scan_part(const int* __restrict__ cnt,
                                                   int* __restrict__ bsum, int N){
  __shared__ int red[256];
  int t = threadIdx.x;
  int lo = blockIdx.x * SCHUNK + t * 8;
  int s = 0;
#pragma unroll
  for (int k = 0; k < 8; ++k){
    int i = lo + k;
    s += (i < N) ? cnt[i] : 0;
  }
  red[t] = s;
  __syncthreads();
  for (int off = 128; off > 0; off >>= 1){
    if (t < off) red[t] += red[t + off];
    __syncthreads();
  }
  if (t == 0) bsum[blockIdx.x] = red[0];
}

__global__ __launch_bounds__(1024) void k_scan_mid(const int* __restrict__ bsum,
                                                   int* __restrict__ boff, int nb,
                                                   int* __restrict__ rp, int N, int E){
  __shared__ int part[1024];
  int t = threadIdx.x;
  part[t] = (t < nb) ? bsum[t] : 0;
  __syncthreads();
  for (int off = 1; off < 1024; off <<= 1){
    int v = (t >= off) ? part[t - off] : 0;
    __syncthreads();
    part[t] += v;
    __syncthreads();
  }
  if (t < nb) boff[t] = (t == 0) ? 0 : part[t - 1];
  if (t == 0) rp[N] = E;
}

__global__ __launch_bounds__(256) void k_scan_apply(const int* __restrict__ cnt,
                                                    const int* __restrict__ boff,
                                                    int* __restrict__ rp,
                                                    float* __restrict__ dinv, int N){
  __shared__ int tsum[256];
  int t = threadIdx.x;
  int lo = blockIdx.x * SCHUNK + t * 8;
  int v[8];
  int s = 0;
#pragma unroll
  for (int k = 0; k < 8; ++k){
    int i = lo + k;
    v[k] = (i < N) ? cnt[i] : 0;
    s += v[k];
  }
  tsum[t] = s;
  __syncthreads();
  for (int off = 1; off < 256; off <<= 1){
    int u = (t >= off) ? tsum[t - off] : 0;
    __syncthreads();
    tsum[t] += u;
    __syncthreads();
  }
  int base = boff[blockIdx.x] + ((t == 0) ? 0 : tsum[t - 1]);
#pragma unroll
  for (int k = 0; k < 8; ++k){
    int i = lo + k;
    if (i < N){
      rp[i] = base;
      dinv[i] = rsqrtf((float)v[k] + 1.0f);
      base += v[k];
    }
  }
}

// fill: consumes cnt as cursor (atomicSub). 4B record: (deg1<<18) | src.
__global__ __launch_bounds__(256) void k_fill(const int* __restrict__ src,
                                              const int* __restrict__ dst, int E,
                                              const int* __restrict__ rp,
                                              int* cnt,
                                              const float* __restrict__ dinv,
                                              unsigned* __restrict__ col){
  int e = blockIdx.x * 256 + threadIdx.x;
  if (e >= E) return;
  int s = src[e], d = dst[e];
  int pos = rp[d] + atomicSub(&cnt[d], 1) - 1;
  float di = dinv[s];                       // = rsqrt(deg1), deg1 = deg+1
  int deg1 = (int)(1.0f / (di * di) + 0.5f);
  col[pos] = ((unsigned)deg1 << 18) | (unsigned)s;
}

// ---- weight prep: fp32 -> fp16 (RTN), bias sum -----------------------------
__global__ __launch_bounds__(256) void k_prep_w(const float* __restrict__ Wc,
                                                const float* __restrict__ Wr,
                                                const float* __restrict__ We,
                                                const float* __restrict__ bc,
                                                const float* __restrict__ br,
                                                _Float16* __restrict__ WcF,
                                                _Float16* __restrict__ WrF,
                                                _Float16* __restrict__ WeF,
                                                float* __restrict__ bias_sum){
  int i = blockIdx.x * 256 + threadIdx.x;
  if (i < HD * HD){
    WcF[i] = (_Float16)Wc[i];
    WrF[i] = (_Float16)Wr[i];
    WeF[i] = (_Float16)We[i];
  }
  if (i < HD) bias_sum[i] = bc[i] + br[i];
}

// ---- per-layer aggregation: U = dinv[dst] * sum_e rsqrt(deg1_src)*XsH[src] -
// One wave per node. Quarter-wave per edge: lane group q = lane>>4 handles
// edges b+q, b+q+4, ...; each lane gathers f16x8 (16B); 16 lanes * 16B = 256B
// row. 2x unroll => 8 gathers in flight per wave. shfl_xor(16,32) combine;
// dinv[node] applied once after the reduce. U written fp16.
__global__ __launch_bounds__(256) void k_agg(const _Float16* __restrict__ XsH,
                                             const float* __restrict__ dinv,
                                             const int* __restrict__ rp,
                                             const unsigned* __restrict__ col,
                                             _Float16* __restrict__ U,
                                             int N){
  int w = threadIdx.x >> 6;
  int lane = threadIdx.x & 63;
  int q = lane >> 4;       // edge slot 0..3
  int ql = lane & 15;      // channel group: cols ql*8 .. ql*8+7
  int node = blockIdx.x * 4 + w;
  if (node >= N) return;

  float acc[8];
#pragma unroll
  for (int i = 0; i < 8; ++i) acc[i] = 0.f;

  int b = rp[node], e = rp[node + 1];
  int j = b + q;
  for (; j + 4 < e; j += 8){
    unsigned r0 = col[j];
    unsigned r1 = col[j + 4];
    float w0 = rsqrtf((float)(r0 >> 18));
    float w1 = rsqrtf((float)(r1 >> 18));
    f16x8 v0 = ((const f16x8*)(XsH + (size_t)(r0 & 0x3FFFFu) * HD))[ql];
    f16x8 v1 = ((const f16x8*)(XsH + (size_t)(r1 & 0x3FFFFu) * HD))[ql];
#pragma unroll
    for (int i = 0; i < 8; ++i) acc[i] = fmaf(w0, (float)v0[i], acc[i]);
#pragma unroll
    for (int i = 0; i < 8; ++i) acc[i] = fmaf(w1, (float)v1[i], acc[i]);
  }
  if (j < e){
    unsigned r0 = col[j];
    float w0 = rsqrtf((float)(r0 >> 18));
    f16x8 v0 = ((const f16x8*)(XsH + (size_t)(r0 & 0x3FFFFu) * HD))[ql];
#pragma unroll
    for (int i = 0; i < 8; ++i) acc[i] = fmaf(w0, (float)v0[i], acc[i]);
  }

  float dn = dinv[node];
#pragma unroll
  for (int i = 0; i < 8; ++i){
    acc[i] += __shfl_xor(acc[i], 16, 64);
    acc[i] += __shfl_xor(acc[i], 32, 64);
    acc[i] *= dn;
  }
  if (q == 0){
    f16x8 o;
#pragma unroll
    for (int i = 0; i < 8; ++i) o[i] = (_Float16)acc[i];
    ((f16x8*)(U + (size_t)node * HD))[ql] = o;
  }
}

// ---- fused fp16 GEMM, weights LDS-staged -----------------------------------
// two=false: out = cvt16(A1f) We^T + bias (encoder; A1f fp32).
// two=true:  A1' = U + (dinv[row]^2-1)*XsH (in-register);
//            out = relu(A1' Wc^T + XsH Wr^T + bias). Writes XsH fp16.
// decode: skip stores, val[row] = dot(out_row, Wd) + bd[0].
__global__ __launch_bounds__(256) void k_gemm(
    const float* __restrict__ A1f,            // encoder input x (fp32) or null
    const _Float16* __restrict__ A1h,         // U (fp16) or null
    const _Float16* A2h,                      // XsH (aliases outXsH) or null
    const _Float16* __restrict__ W1,          // WcF or WeF
    const _Float16* __restrict__ W2,          // WrF or null
    const float* __restrict__ dinvp,
    const float* __restrict__ bias,
    _Float16* outXsH,
    const float* __restrict__ Wd, const float* __restrict__ bd,
    float* __restrict__ val,
    int N, int relu, int decode){
  __shared__ _Float16 wsm[2 * HD * HD];       // 64 KB: [matrix][row][slot^]
  f16x8* smv = (f16x8*)wsm;

  // cooperative swizzled weight staging (all threads; barrier is convergent)
  {
    int t = threadIdx.x;
    const f16x8* g1 = (const f16x8*)W1;
    for (int i = t; i < HD * HD / 8; i += 256){
      int row = i >> 4, slot = i & 15;
      smv[(row << 4) | (slot ^ (row & 7))] = g1[i];
    }
    if (W2){
      const f16x8* g2 = (const f16x8*)W2;
      for (int i = t; i < HD * HD / 8; i += 256){
        int row = i >> 4, slot = i & 15;
        smv[2048 + ((row << 4) | (slot ^ (row & 7)))] = g2[i];
      }
    }
  }
  __syncthreads();

  int wid = blockIdx.x * 4 + (threadIdx.x >> 6);
  int row0 = wid * 32;
  if (row0 >= N) return;
  int lane = threadIdx.x & 63;
  int r = lane & 15;
  int kg = lane >> 4;

  f32x4 acc[2][8];
#pragma unroll
  for (int s = 0; s < 2; ++s)
#pragma unroll
    for (int c = 0; c < 8; ++c) acc[s][c] = (f32x4)0.0f;

  const bool two = (A2h != nullptr);
  float sr[2] = {0.f, 0.f};
  if (two){
#pragma unroll
    for (int s = 0; s < 2; ++s){
      float d = dinvp[row0 + s * 16 + r];
      sr[s] = d * d - 1.0f;
    }
  }

#pragma unroll
  for (int kst = 0; kst < 4; ++kst){
    int k0 = kst * 32 + kg * 8;
    f16x8 a1[2], a2[2];
#pragma unroll
    for (int s = 0; s < 2; ++s){
      size_t ao = (size_t)(row0 + s * 16 + r) * HD + k0;
      if (two){
        f16x8 uh = *(const f16x8*)(A1h + ao);
        f16x8 xv = *(const f16x8*)(A2h + ao);
        a2[s] = xv;
#pragma unroll
        for (int i = 0; i < 8; ++i)
          a1[s][i] = (_Float16)fmaf(sr[s], (float)xv[i], (float)uh[i]);
      } else {
        f32x8 u = *(const f32x8*)(A1f + ao);
#pragma unroll
        for (int i = 0; i < 8; ++i) a1[s][i] = (_Float16)u[i];
      }
    }
    int swz = (kst * 4 + kg) ^ (r & 7);
#pragma unroll
    for (int ct = 0; ct < 8; ++ct){
      int ridx = ((ct * 16 + r) << 4) | swz;
      f16x8 b1 = smv[ridx];
#pragma unroll
      for (int s = 0; s < 2; ++s)
        acc[s][ct] = __builtin_amdgcn_mfma_f32_16x16x32_f16(a1[s], b1, acc[s][ct], 0, 0, 0);
      if (two){
        f16x8 b2 = smv[2048 + ridx];
#pragma unroll
        for (int s = 0; s < 2; ++s)
          acc[s][ct] = __builtin_amdgcn_mfma_f32_16x16x32_f16(a2[s], b2, acc[s][ct], 0, 0, 0);
      }
    }
  }

  // epilogue: C/D layout col = lane&15, row = kg*4 + reg
  float rowp[2][4] = {{0.f,0.f,0.f,0.f},{0.f,0.f,0.f,0.f}};
#pragma unroll
  for (int s = 0; s < 2; ++s){
#pragma unroll
    for (int ct = 0; ct < 8; ++ct){
      int cc = ct * 16 + r;
      float bv = bias[cc];
      float wdv = decode ? Wd[cc] : 0.f;
#pragma unroll
      for (int j = 0; j < 4; ++j){
        float v = acc[s][ct][j] + bv;
        if (relu) v = fmaxf(v, 0.0f);
        if (decode){
          rowp[s][j] += v * wdv;
        } else {
          int rr = row0 + s * 16 + kg * 4 + j;
          outXsH[(size_t)rr * HD + cc] = (_Float16)v;
        }
      }
    }
  }
  if (decode){
    float bd0 = bd[0];
#pragma unroll
    for (int s = 0; s < 2; ++s)
#pragma unroll
      for (int j = 0; j < 4; ++j){
        float t = rowp[s][j];
        t += __shfl_xor(t, 1, 64);
        t += __shfl_xor(t, 2, 64);
        t += __shfl_xor(t, 4, 64);
        t += __shfl_xor(t, 8, 64);
        if (r == 0) val[row0 + s * 16 + kg * 4 + j] = t + bd0;
      }
  }
}

// ---- pooling: LDS histogram per block, few global atomics ------------------
#define POOL_CHUNK 1024
__global__ __launch_bounds__(256) void k_pool(const float* __restrict__ val,
                                              const int* __restrict__ batch,
                                              float* __restrict__ out, int N, int G){
  __shared__ float acc[4096];
  int t = threadIdx.x;
  int lo = blockIdx.x * POOL_CHUNK;
  int hi = min(lo + POOL_CHUNK, N);
  if (G <= 4096){
    for (int i = t; i < G; i += 256) acc[i] = 0.f;
    __syncthreads();
    for (int i = lo + t; i < hi; i += 256) atomicAdd(&acc[batch[i]], val[i]);
    __syncthreads();
    for (int i = t; i < G; i += 256){
      float v = acc[i];
      if (v != 0.f) atomicAdd(&out[i], v);
    }
  } else {
    for (int i = lo + t; i < hi; i += 256) atomicAdd(&out[batch[i]], val[i]);
  }
}

// ---- launcher ---------------------------------------------------------------
extern "C" void kernel_launch(void* const* d_in, const int* in_sizes, int n_in,
                              void* d_out, int out_size, void* d_ws, size_t ws_size,
                              hipStream_t stream){
  const float* x      = (const float*)d_in[0];
  const int*   ei     = (const int*)d_in[1];
  const int*   batch  = (const int*)d_in[2];
  const float* W_enc  = (const float*)d_in[3];
  const float* b_enc  = (const float*)d_in[4];
  const float* W_conv = (const float*)d_in[5];
  const float* b_conv = (const float*)d_in[6];
  const float* W_res  = (const float*)d_in[7];
  const float* b_res  = (const float*)d_in[8];
  const float* W_dec  = (const float*)d_in[9];
  const float* b_dec  = (const float*)d_in[10];

  const int N = in_sizes[0] / HD;
  const int E = in_sizes[1] / 2;
  float* out = (float*)d_out;

  char* ws = (char*)d_ws;
  size_t off = 0;
  auto alloc = [&](size_t bytes) -> char* {
    char* p = ws + off;
    off += (bytes + 255) & ~(size_t)255;
    return p;
  };
  int*   cnt   = (int*)  alloc((size_t)N * 4);
  int*   rp    = (int*)  alloc(((size_t)N + 1) * 4);
  float* dinv  = (float*)alloc((size_t)N * 4);
  int*   bsum  = (int*)  alloc(1024 * 4);
  int*   boff  = (int*)  alloc(1024 * 4);
  unsigned* col= (unsigned*)alloc((size_t)E * 4);
  _Float16* XsH= (_Float16*)alloc((size_t)N * HD * 2);
  _Float16* U  = (_Float16*)alloc((size_t)N * HD * 2);
  float* val   = (float*)alloc((size_t)N * 4);
  _Float16* WcF = (_Float16*)alloc((size_t)HD * HD * 2);
  _Float16* WrF = (_Float16*)alloc((size_t)HD * HD * 2);
  _Float16* WeF = (_Float16*)alloc((size_t)HD * HD * 2);
  float* bias_sum = (float*)alloc((size_t)HD * 4);

  hipMemsetAsync(cnt, 0, (size_t)N * 4, stream);
  hipMemsetAsync(out, 0, (size_t)out_size * 4, stream);

  const int* src = ei;
  const int* dst = ei + E;

  int nb = (N + SCHUNK - 1) / SCHUNK;

  k_deg       <<<(E + 255) / 256, 256, 0, stream>>>(dst, E, cnt);
  k_scan_part <<<nb, 256, 0, stream>>>(cnt, bsum, N);
  k_scan_mid  <<<1, 1024, 0, stream>>>(bsum, boff, nb, rp, N, E);
  k_scan_apply<<<nb, 256, 0, stream>>>(cnt, boff, rp, dinv, N);
  k_fill      <<<(E + 255) / 256, 256, 0, stream>>>(src, dst, E, rp, cnt, dinv, col);
  k_prep_w    <<<(HD * HD + 255) / 256, 256, 0, stream>>>(W_conv, W_res, W_enc, b_conv, b_res,
                                                          WcF, WrF, WeF, bias_sum);

  int gemm_blocks = ((N + 31) / 32 + 3) / 4;
  int node_blocks = (N + 3) / 4;

  // encoder: XsH = fp16(x @ W_enc^T + b_enc)   (no relu, no self-fold)
  k_gemm<<<gemm_blocks, 256, 0, stream>>>(x, nullptr, nullptr, WeF, nullptr,
                                          nullptr, b_enc, XsH,
                                          nullptr, nullptr, nullptr, N, 0, 0);

  for (int l = 0; l < 5; ++l){
    k_agg<<<node_blocks, 256, 0, stream>>>(XsH, dinv, rp, col, U, N);
    int last = (l == 4);
    k_gemm<<<gemm_blocks, 256, 0, stream>>>(nullptr, U, XsH, WcF, WrF,
                                            dinv, bias_sum, XsH,
                                            W_dec, b_dec, val, N, 1, last);
  }

  k_pool<<<(N + POOL_CHUNK - 1) / POOL_CHUNK, 256, 0, stream>>>(val, batch, out, N, out_size);
}

// Round 7
// 642.602 us; speedup vs baseline: 2.9523x; 1.0030x over previous
//
#include <hip/hip_runtime.h>
#include <hip/hip_bf16.h>
#include <stdint.h>

// GraphCON-GCN on MI355X.
// Algebra: with DT=ALPHA=GAMMA=1, Xs_{l+1} = relu(gcn+res); Y drops out.
// z = (A.Xs) Wc^T + (dinv^2-1) Xs Wc^T + Xs Wr^T + (b_c+b_r)  [self-term folded
// into the GEMM in-register]. State fp16 (XsH); agg gathers fp16, U fp16.
// Edge record = 4B: (deg+1)<<18 | src; dinv[src]=rsqrt(deg+1) recomputed
// bit-exactly in agg, dinv[dst] factored out of the edge loop.
// GEMM: fp16 MFMA (16x16x32_f16, fp32 accum), weights LDS-staged (swizzled).
// Decode fused into final GEMM; pooling via LDS histogram.

#define HD 128
#define SCHUNK 2048   // scan elements per block (256 thr * 8)

typedef __attribute__((ext_vector_type(4))) float f32x4;
typedef __attribute__((ext_vector_type(8))) float f32x8;
typedef __attribute__((ext_vector_type(8))) _Float16 f16x8;

// ---- CSR build ------------------------------------------------------------
__global__ __launch_bounds__(256) void k_deg(const int* __restrict__ dst, int E,
                                             int* __restrict__ cnt){
  int e = blockIdx.x * 256 + threadIdx.x;
  if (e < E) atomicAdd(&cnt[dst[e]], 1);
}

__global__ __launch_bounds__(256) void k_scan_part(const int* __restrict__ cnt,
                                                   int* __restrict__ bsum, int N){
  __shared__ int red[256];
  int t = threadIdx.x;
  int lo = blockIdx.x * SCHUNK + t * 8;
  int s = 0;
#pragma unroll
  for (int k = 0; k < 8; ++k){
    int i = lo + k;
    s += (i < N) ? cnt[i] : 0;
  }
  red[t] = s;
  __syncthreads();
  for (int off = 128; off > 0; off >>= 1){
    if (t < off) red[t] += red[t + off];
    __syncthreads();
  }
  if (t == 0) bsum[blockIdx.x] = red[0];
}

__global__ __launch_bounds__(1024) void k_scan_mid(const int* __restrict__ bsum,
                                                   int* __restrict__ boff, int nb,
                                                   int* __restrict__ rp, int N, int E){
  __shared__ int part[1024];
  int t = threadIdx.x;
  part[t] = (t < nb) ? bsum[t] : 0;
  __syncthreads();
  for (int off = 1; off < 1024; off <<= 1){
    int v = (t >= off) ? part[t - off] : 0;
    __syncthreads();
    part[t] += v;
    __syncthreads();
  }
  if (t < nb) boff[t] = (t == 0) ? 0 : part[t - 1];
  if (t == 0) rp[N] = E;
}

__global__ __launch_bounds__(256) void k_scan_apply(const int* __restrict__ cnt,
                                                    const int* __restrict__ boff,
                                                    int* __restrict__ rp,
                                                    float* __restrict__ dinv, int N){
  __shared__ int tsum[256];
  int t = threadIdx.x;
  int lo = blockIdx.x * SCHUNK + t * 8;
  int v[8];
  int s = 0;
#pragma unroll
  for (int k = 0; k < 8; ++k){
    int i = lo + k;
    v[k] = (i < N) ? cnt[i] : 0;
    s += v[k];
  }
  tsum[t] = s;
  __syncthreads();
  for (int off = 1; off < 256; off <<= 1){
    int u = (t >= off) ? tsum[t - off] : 0;
    __syncthreads();
    tsum[t] += u;
    __syncthreads();
  }
  int base = boff[blockIdx.x] + ((t == 0) ? 0 : tsum[t - 1]);
#pragma unroll
  for (int k = 0; k < 8; ++k){
    int i = lo + k;
    if (i < N){
      rp[i] = base;
      dinv[i] = rsqrtf((float)v[k] + 1.0f);
      base += v[k];
    }
  }
}

// fill: consumes cnt as cursor (atomicSub). 4B record: (deg1<<18) | src.
__global__ __launch_bounds__(256) void k_fill(const int* __restrict__ src,
                                              const int* __restrict__ dst, int E,
                                              const int* __restrict__ rp,
                                              int* cnt,
                                              const float* __restrict__ dinv,
                                              unsigned* __restrict__ col){
  int e = blockIdx.x * 256 + threadIdx.x;
  if (e >= E) return;
  int s = src[e], d = dst[e];
  int pos = rp[d] + atomicSub(&cnt[d], 1) - 1;
  float di = dinv[s];                       // = rsqrt(deg1), deg1 = deg+1
  int deg1 = (int)(1.0f / (di * di) + 0.5f);
  col[pos] = ((unsigned)deg1 << 18) | (unsigned)s;
}

// ---- weight prep: fp32 -> fp16 (RTN), bias sum -----------------------------
__global__ __launch_bounds__(256) void k_prep_w(const float* __restrict__ Wc,
                                                const float* __restrict__ Wr,
                                                const float* __restrict__ We,
                                                const float* __restrict__ bc,
                                                const float* __restrict__ br,
                                                _Float16* __restrict__ WcF,
                                                _Float16* __restrict__ WrF,
                                                _Float16* __restrict__ WeF,
                                                float* __restrict__ bias_sum){
  int i = blockIdx.x * 256 + threadIdx.x;
  if (i < HD * HD){
    WcF[i] = (_Float16)Wc[i];
    WrF[i] = (_Float16)Wr[i];
    WeF[i] = (_Float16)We[i];
  }
  if (i < HD) bias_sum[i] = bc[i] + br[i];
}

// ---- per-layer aggregation: U = dinv[dst] * sum_e rsqrt(deg1_src)*XsH[src] -
// One wave per node. Quarter-wave per edge: lane group q = lane>>4 handles
// edges b+q, b+q+4, ...; each lane gathers f16x8 (16B); 16 lanes * 16B = 256B
// row. 2x unroll => 8 gathers in flight per wave. shfl_xor(16,32) combine;
// dinv[node] applied once after the reduce. U written fp16.
__global__ __launch_bounds__(256) void k_agg(const _Float16* __restrict__ XsH,
                                             const float* __restrict__ dinv,
                                             const int* __restrict__ rp,
                                             const unsigned* __restrict__ col,
                                             _Float16* __restrict__ U,
                                             int N){
  int w = threadIdx.x >> 6;
  int lane = threadIdx.x & 63;
  int q = lane >> 4;       // edge slot 0..3
  int ql = lane & 15;      // channel group: cols ql*8 .. ql*8+7
  int node = blockIdx.x * 4 + w;
  if (node >= N) return;

  float acc[8];
#pragma unroll
  for (int i = 0; i < 8; ++i) acc[i] = 0.f;

  int b = rp[node], e = rp[node + 1];
  int j = b + q;
  for (; j + 4 < e; j += 8){
    unsigned r0 = col[j];
    unsigned r1 = col[j + 4];
    float w0 = rsqrtf((float)(r0 >> 18));
    float w1 = rsqrtf((float)(r1 >> 18));
    f16x8 v0 = ((const f16x8*)(XsH + (size_t)(r0 & 0x3FFFFu) * HD))[ql];
    f16x8 v1 = ((const f16x8*)(XsH + (size_t)(r1 & 0x3FFFFu) * HD))[ql];
#pragma unroll
    for (int i = 0; i < 8; ++i) acc[i] = fmaf(w0, (float)v0[i], acc[i]);
#pragma unroll
    for (int i = 0; i < 8; ++i) acc[i] = fmaf(w1, (float)v1[i], acc[i]);
  }
  if (j < e){
    unsigned r0 = col[j];
    float w0 = rsqrtf((float)(r0 >> 18));
    f16x8 v0 = ((const f16x8*)(XsH + (size_t)(r0 & 0x3FFFFu) * HD))[ql];
#pragma unroll
    for (int i = 0; i < 8; ++i) acc[i] = fmaf(w0, (float)v0[i], acc[i]);
  }

  float dn = dinv[node];
#pragma unroll
  for (int i = 0; i < 8; ++i){
    acc[i] += __shfl_xor(acc[i], 16, 64);
    acc[i] += __shfl_xor(acc[i], 32, 64);
    acc[i] *= dn;
  }
  if (q == 0){
    f16x8 o;
#pragma unroll
    for (int i = 0; i < 8; ++i) o[i] = (_Float16)acc[i];
    ((f16x8*)(U + (size_t)node * HD))[ql] = o;
  }
}

// ---- fused fp16 GEMM, weights LDS-staged -----------------------------------
// two=false: out = cvt16(A1f) We^T + bias (encoder; A1f fp32).
// two=true:  A1' = U + (dinv[row]^2-1)*XsH (in-register);
//            out = relu(A1' Wc^T + XsH Wr^T + bias). Writes XsH fp16.
// decode: skip stores, val[row] = dot(out_row, Wd) + bd[0].
__global__ __launch_bounds__(256) void k_gemm(
    const float* __restrict__ A1f,            // encoder input x (fp32) or null
    const _Float16* __restrict__ A1h,         // U (fp16) or null
    const _Float16* A2h,                      // XsH (aliases outXsH) or null
    const _Float16* __restrict__ W1,          // WcF or WeF
    const _Float16* __restrict__ W2,          // WrF or null
    const float* __restrict__ dinvp,
    const float* __restrict__ bias,
    _Float16* outXsH,
    const float* __restrict__ Wd, const float* __restrict__ bd,
    float* __restrict__ val,
    int N, int relu, int decode){
  __shared__ _Float16 wsm[2 * HD * HD];       // 64 KB: [matrix][row][slot^]
  f16x8* smv = (f16x8*)wsm;

  // cooperative swizzled weight staging (all threads; barrier is convergent)
  {
    int t = threadIdx.x;
    const f16x8* g1 = (const f16x8*)W1;
    for (int i = t; i < HD * HD / 8; i += 256){
      int row = i >> 4, slot = i & 15;
      smv[(row << 4) | (slot ^ (row & 7))] = g1[i];
    }
    if (W2){
      const f16x8* g2 = (const f16x8*)W2;
      for (int i = t; i < HD * HD / 8; i += 256){
        int row = i >> 4, slot = i & 15;
        smv[2048 + ((row << 4) | (slot ^ (row & 7)))] = g2[i];
      }
    }
  }
  __syncthreads();

  int wid = blockIdx.x * 4 + (threadIdx.x >> 6);
  int row0 = wid * 32;
  if (row0 >= N) return;
  int lane = threadIdx.x & 63;
  int r = lane & 15;
  int kg = lane >> 4;

  f32x4 acc[2][8];
#pragma unroll
  for (int s = 0; s < 2; ++s)
#pragma unroll
    for (int c = 0; c < 8; ++c) acc[s][c] = (f32x4)0.0f;

  const bool two = (A2h != nullptr);
  float sr[2] = {0.f, 0.f};
  if (two){
#pragma unroll
    for (int s = 0; s < 2; ++s){
      float d = dinvp[row0 + s * 16 + r];
      sr[s] = d * d - 1.0f;
    }
  }

#pragma unroll
  for (int kst = 0; kst < 4; ++kst){
    int k0 = kst * 32 + kg * 8;
    f16x8 a1[2], a2[2];
#pragma unroll
    for (int s = 0; s < 2; ++s){
      size_t ao = (size_t)(row0 + s * 16 + r) * HD + k0;
      if (two){
        f16x8 uh = *(const f16x8*)(A1h + ao);
        f16x8 xv = *(const f16x8*)(A2h + ao);
        a2[s] = xv;
#pragma unroll
        for (int i = 0; i < 8; ++i)
          a1[s][i] = (_Float16)fmaf(sr[s], (float)xv[i], (float)uh[i]);
      } else {
        f32x8 u = *(const f32x8*)(A1f + ao);
#pragma unroll
        for (int i = 0; i < 8; ++i) a1[s][i] = (_Float16)u[i];
      }
    }
    int swz = (kst * 4 + kg) ^ (r & 7);
#pragma unroll
    for (int ct = 0; ct < 8; ++ct){
      int ridx = ((ct * 16 + r) << 4) | swz;
      f16x8 b1 = smv[ridx];
#pragma unroll
      for (int s = 0; s < 2; ++s)
        acc[s][ct] = __builtin_amdgcn_mfma_f32_16x16x32_f16(a1[s], b1, acc[s][ct], 0, 0, 0);
      if (two){
        f16x8 b2 = smv[2048 + ridx];
#pragma unroll
        for (int s = 0; s < 2; ++s)
          acc[s][ct] = __builtin_amdgcn_mfma_f32_16x16x32_f16(a2[s], b2, acc[s][ct], 0, 0, 0);
      }
    }
  }

  // epilogue: C/D layout col = lane&15, row = kg*4 + reg
  float rowp[2][4] = {{0.f,0.f,0.f,0.f},{0.f,0.f,0.f,0.f}};
#pragma unroll
  for (int s = 0; s < 2; ++s){
#pragma unroll
    for (int ct = 0; ct < 8; ++ct){
      int cc = ct * 16 + r;
      float bv = bias[cc];
      float wdv = decode ? Wd[cc] : 0.f;
#pragma unroll
      for (int j = 0; j < 4; ++j){
        float v = acc[s][ct][j] + bv;
        if (relu) v = fmaxf(v, 0.0f);
        if (decode){
          rowp[s][j] += v * wdv;
        } else {
          int rr = row0 + s * 16 + kg * 4 + j;
          outXsH[(size_t)rr * HD + cc] = (_Float16)v;
        }
      }
    }
  }
  if (decode){
    float bd0 = bd[0];
#pragma unroll
    for (int s = 0; s < 2; ++s)
#pragma unroll
      for (int j = 0; j < 4; ++j){
        float t = rowp[s][j];
        t += __shfl_xor(t, 1, 64);
        t += __shfl_xor(t, 2, 64);
        t += __shfl_xor(t, 4, 64);
        t += __shfl_xor(t, 8, 64);
        if (r == 0) val[row0 + s * 16 + kg * 4 + j] = t + bd0;
      }
  }
}

// ---- pooling: LDS histogram per block, few global atomics ------------------
#define POOL_CHUNK 1024
__global__ __launch_bounds__(256) void k_pool(const float* __restrict__ val,
                                              const int* __restrict__ batch,
                                              float* __restrict__ out, int N, int G){
  __shared__ float acc[4096];
  int t = threadIdx.x;
  int lo = blockIdx.x * POOL_CHUNK;
  int hi = min(lo + POOL_CHUNK, N);
  if (G <= 4096){
    for (int i = t; i < G; i += 256) acc[i] = 0.f;
    __syncthreads();
    for (int i = lo + t; i < hi; i += 256) atomicAdd(&acc[batch[i]], val[i]);
    __syncthreads();
    for (int i = t; i < G; i += 256){
      float v = acc[i];
      if (v != 0.f) atomicAdd(&out[i], v);
    }
  } else {
    for (int i = lo + t; i < hi; i += 256) atomicAdd(&out[batch[i]], val[i]);
  }
}

// ---- launcher ---------------------------------------------------------------
extern "C" void kernel_launch(void* const* d_in, const int* in_sizes, int n_in,
                              void* d_out, int out_size, void* d_ws, size_t ws_size,
                              hipStream_t stream){
  const float* x      = (const float*)d_in[0];
  const int*   ei     = (const int*)d_in[1];
  const int*   batch  = (const int*)d_in[2];
  const float* W_enc  = (const float*)d_in[3];
  const float* b_enc  = (const float*)d_in[4];
  const float* W_conv = (const float*)d_in[5];
  const float* b_conv = (const float*)d_in[6];
  const float* W_res  = (const float*)d_in[7];
  const float* b_res  = (const float*)d_in[8];
  const float* W_dec  = (const float*)d_in[9];
  const float* b_dec  = (const float*)d_in[10];

  const int N = in_sizes[0] / HD;
  const int E = in_sizes[1] / 2;
  float* out = (float*)d_out;

  char* ws = (char*)d_ws;
  size_t off = 0;
  auto alloc = [&](size_t bytes) -> char* {
    char* p = ws + off;
    off += (bytes + 255) & ~(size_t)255;
    return p;
  };
  int*   cnt   = (int*)  alloc((size_t)N * 4);
  int*   rp    = (int*)  alloc(((size_t)N + 1) * 4);
  float* dinv  = (float*)alloc((size_t)N * 4);
  int*   bsum  = (int*)  alloc(1024 * 4);
  int*   boff  = (int*)  alloc(1024 * 4);
  unsigned* col= (unsigned*)alloc((size_t)E * 4);
  _Float16* XsH= (_Float16*)alloc((size_t)N * HD * 2);
  _Float16* U  = (_Float16*)alloc((size_t)N * HD * 2);
  float* val   = (float*)alloc((size_t)N * 4);
  _Float16* WcF = (_Float16*)alloc((size_t)HD * HD * 2);
  _Float16* WrF = (_Float16*)alloc((size_t)HD * HD * 2);
  _Float16* WeF = (_Float16*)alloc((size_t)HD * HD * 2);
  float* bias_sum = (float*)alloc((size_t)HD * 4);

  hipMemsetAsync(cnt, 0, (size_t)N * 4, stream);
  hipMemsetAsync(out, 0, (size_t)out_size * 4, stream);

  const int* src = ei;
  const int* dst = ei + E;

  int nb = (N + SCHUNK - 1) / SCHUNK;

  k_deg       <<<(E + 255) / 256, 256, 0, stream>>>(dst, E, cnt);
  k_scan_part <<<nb, 256, 0, stream>>>(cnt, bsum, N);
  k_scan_mid  <<<1, 1024, 0, stream>>>(bsum, boff, nb, rp, N, E);
  k_scan_apply<<<nb, 256, 0, stream>>>(cnt, boff, rp, dinv, N);
  k_fill      <<<(E + 255) / 256, 256, 0, stream>>>(src, dst, E, rp, cnt, dinv, col);
  k_prep_w    <<<(HD * HD + 255) / 256, 256, 0, stream>>>(W_conv, W_res, W_enc, b_conv, b_res,
                                                          WcF, WrF, WeF, bias_sum);

  int gemm_blocks = ((N + 31) / 32 + 3) / 4;
  int node_blocks = (N + 3) / 4;

  // encoder: XsH = fp16(x @ W_enc^T + b_enc)   (no relu, no self-fold)
  k_gemm<<<gemm_blocks, 256, 0, stream>>>(x, nullptr, nullptr, WeF, nullptr,
                                          nullptr, b_enc, XsH,
                                          nullptr, nullptr, nullptr, N, 0, 0);

  for (int l = 0; l < 5; ++l){
    k_agg<<<node_blocks, 256, 0, stream>>>(XsH, dinv, rp, col, U, N);
    int last = (l == 4);
    k_gemm<<<gemm_blocks, 256, 0, stream>>>(nullptr, U, XsH, WcF, WrF,
                                            dinv, bias_sum, XsH,
                                            W_dec, b_dec, val, N, 1, last);
  }

  k_pool<<<(N + POOL_CHUNK - 1) / POOL_CHUNK, 256, 0, stream>>>(val, batch, out, N, out_size);
}